// Round 7
// baseline (146205.127 us; speedup 1.0000x reference)
//
#include <hip/hip_runtime.h>
#include <hip/hip_bf16.h>
#include <math.h>

#define B_ 64
#define T_ 104
#define FEAT_ 20
#define PEMB_ 64
#define COND_ 256
#define SUB_ 40
#define NBF_ 100
#define STEPS_ 400

typedef short short8 __attribute__((ext_vector_type(8)));
typedef float floatx4 __attribute__((ext_vector_type(4)));
typedef int intx4 __attribute__((ext_vector_type(4)));

__device__ inline unsigned short f2bf(float x){
  unsigned int u = __float_as_uint(x);
  unsigned int r = (u + 0x7fffu + ((u >> 16) & 1u)) >> 16;
  return (unsigned short)r;
}
__device__ inline float fast_tanh(float x){
  float e = __expf(2.f*x);
  return 1.f - 2.f*__builtin_amdgcn_rcpf(e + 1.f);
}
__device__ inline float fast_sigm(float x){
  return __builtin_amdgcn_rcpf(1.f + __expf(-x));
}
__device__ inline floatx4 mfma16(short8 a, short8 b, floatx4 c){
  return __builtin_amdgcn_mfma_f32_16x16x32_bf16(a, b, c, 0, 0, 0);
}
// dual-store: plain (local XCD L2, write-through L1) + agent (MALL)
__device__ inline void st_dual(unsigned int* pi, unsigned int* pm, unsigned int v){
  pi[0] = v;
  __hip_atomic_store(pm, v, __ATOMIC_RELAXED, __HIP_MEMORY_SCOPE_AGENT);
}

// Poll two 8-word chunks (offsets o0,o1 in u32) of an epoch-stamped payload
// ((stamp<<16)|bf16). Intra mode: sc0 loads (L1-bypass, local-L2 hit). If the
// data never arrives (wrong placement / wrong cache model), escalate sticky to
// the MALL copy (sc0 sc1). Returns 8 packed bf16x2 words.
__device__ inline void poll_pair(const unsigned int* bi, const unsigned int* bm,
                                 int o0, int o1, unsigned int tgt,
                                 unsigned int* w8, bool& mall){
  int it = 0;
  for(;;){
    const unsigned int* p0 = (mall ? bm : bi) + o0;
    const unsigned int* p1 = (mall ? bm : bi) + o1;
    intx4 a0,a1,b0,b1;
    if (!mall){
      asm volatile(
        "global_load_dwordx4 %0, %4, off sc0\n\t"
        "global_load_dwordx4 %1, %4, off offset:16 sc0\n\t"
        "global_load_dwordx4 %2, %5, off sc0\n\t"
        "global_load_dwordx4 %3, %5, off offset:16 sc0\n\t"
        "s_waitcnt vmcnt(0)"
        : "=&v"(a0), "=&v"(a1), "=&v"(b0), "=&v"(b1)
        : "v"(p0), "v"(p1) : "memory");
    } else {
      asm volatile(
        "global_load_dwordx4 %0, %4, off sc0 sc1\n\t"
        "global_load_dwordx4 %1, %4, off offset:16 sc0 sc1\n\t"
        "global_load_dwordx4 %2, %5, off sc0 sc1\n\t"
        "global_load_dwordx4 %3, %5, off offset:16 sc0 sc1\n\t"
        "s_waitcnt vmcnt(0)"
        : "=&v"(a0), "=&v"(a1), "=&v"(b0), "=&v"(b1)
        : "v"(p0), "v"(p1) : "memory");
    }
    unsigned int m;
    m  = (((unsigned)a0.x>>16)^tgt) | (((unsigned)a0.y>>16)^tgt)
       | (((unsigned)a0.z>>16)^tgt) | (((unsigned)a0.w>>16)^tgt);
    m |= (((unsigned)a1.x>>16)^tgt) | (((unsigned)a1.y>>16)^tgt)
       | (((unsigned)a1.z>>16)^tgt) | (((unsigned)a1.w>>16)^tgt);
    m |= (((unsigned)b0.x>>16)^tgt) | (((unsigned)b0.y>>16)^tgt)
       | (((unsigned)b0.z>>16)^tgt) | (((unsigned)b0.w>>16)^tgt);
    m |= (((unsigned)b1.x>>16)^tgt) | (((unsigned)b1.y>>16)^tgt)
       | (((unsigned)b1.z>>16)^tgt) | (((unsigned)b1.w>>16)^tgt);
    if (m == 0u){
      w8[0]=((unsigned)a0.x&0xFFFFu)|((unsigned)a0.y<<16);
      w8[1]=((unsigned)a0.z&0xFFFFu)|((unsigned)a0.w<<16);
      w8[2]=((unsigned)a1.x&0xFFFFu)|((unsigned)a1.y<<16);
      w8[3]=((unsigned)a1.z&0xFFFFu)|((unsigned)a1.w<<16);
      w8[4]=((unsigned)b0.x&0xFFFFu)|((unsigned)b0.y<<16);
      w8[5]=((unsigned)b0.z&0xFFFFu)|((unsigned)b0.w<<16);
      w8[6]=((unsigned)b1.x&0xFFFFu)|((unsigned)b1.y<<16);
      w8[7]=((unsigned)b1.z&0xFFFFu)|((unsigned)b1.w<<16);
      return;
    }
    if (!mall){ if (++it > 8192) mall = true; }
    else __builtin_amdgcn_s_sleep(1);
  }
}

// ---------------- phase embedding ----------------
__global__ void k_phase(const int* __restrict__ period, const float* __restrict__ rshift,
                        float* __restrict__ pr, float* __restrict__ pi){
  int b = blockIdx.x;
  __shared__ float cumf[NBF_], w0f[NBF_];
  if (threadIdx.x == 0){
    double acc = 2.0*M_PI*(double)rshift[b];
    for (int f = 0; f < NBF_; ++f){
      double w0 = 2.0*M_PI/(double)period[b*T_ + 3 + f];
      cumf[f] = (float)fmod(acc, 2.0*M_PI);
      w0f[f] = (float)w0;
      acc += 160.0*w0;
    }
  }
  __syncthreads();
  for (int e = threadIdx.x; e < NBF_*160; e += blockDim.x){
    int f = e/160, j = e - f*160;
    float ph = cumf[f] + w0f[f]*(float)j;
    int s = f*4 + j/40, u = j%40;
    pr[((size_t)b*STEPS_ + s)*SUB_ + u] = cosf(ph);
    pi[((size_t)b*STEPS_ + s)*SUB_ + u] = sinf(ph);
  }
}

// ---------------- prep: transpose conv weights ----------------
__global__ void k_prep(const float* __restrict__ c1w, const float* __restrict__ c2w,
                       float* __restrict__ w1t, float* __restrict__ w2t){
  size_t tid = (size_t)blockIdx.x*blockDim.x + threadIdx.x;
  size_t nt = (size_t)gridDim.x*blockDim.x;
  for (size_t e = tid; e < 768u*256u; e += nt){
    int kk = (int)(e >> 8), o = (int)(e & 255);
    int i = kk & 255, kc = kk >> 8;
    w1t[e] = c1w[(size_t)o*768 + i*3 + kc];
    w2t[e] = c2w[(size_t)o*768 + i*3 + kc];
  }
}

// ---------------- generic fp32 tiled GEMM (M x K x 256) ----------------
template<int MODE>
__global__ __launch_bounds__(256) void k_gemm(
    const float* __restrict__ a0, const float* __restrict__ a1, const float* __restrict__ a2,
    const int* __restrict__ ip,
    const float* __restrict__ Bm, const float* __restrict__ bias, float* __restrict__ C)
{
  constexpr int KT = (MODE==0) ? 6 : (MODE==1||MODE==2) ? 48 : (MODE==3) ? 16 : 21;
  __shared__ float As[16][68];
  __shared__ float Bs[16][68];
  int tid = threadIdx.x;
  int m0 = blockIdx.x*64, n0 = blockIdx.y*64;
  int tx = tid & 15, ty = tid >> 4;
  float acc[4][4] = {};
  int am = m0 + (tid >> 2);
  int akq = (tid & 3)*4;
  int bk = tid >> 4;
  int bn4 = (tid & 15)*4;

  for (int kt = 0; kt < KT; ++kt){
    int kbase = kt*16;
    float av[4];
    {
      int k0 = kbase + akq;
      if constexpr (MODE==0){
        if (k0 < 20){
          const float* p = a0 + (size_t)am*FEAT_ + k0;
          #pragma unroll
          for (int u=0;u<4;++u) av[u] = p[u];
        } else if (k0 < 84){
          const float* p = a1 + (size_t)ip[am]*PEMB_ + (k0-20);
          #pragma unroll
          for (int u=0;u<4;++u) av[u] = p[u];
        } else { av[0]=av[1]=av[2]=av[3]=0.f; }
      } else if constexpr (MODE==1){
        int b = am/102, t2 = am - b*102;
        int i = k0 & 255, kc = k0 >> 8;
        const float* p = a0 + ((size_t)(b*T_ + t2 + kc))*COND_ + i;
        #pragma unroll
        for (int u=0;u<4;++u) av[u] = p[u];
      } else if constexpr (MODE==2){
        int b = am/100, t2 = am - b*100;
        int i = k0 & 255, kc = k0 >> 8;
        const float* p = a0 + ((size_t)(b*102 + t2 + kc))*COND_ + i;
        #pragma unroll
        for (int u=0;u<4;++u) av[u] = p[u];
      } else if constexpr (MODE==3){
        const float* p = a0 + (size_t)am*COND_ + k0;
        #pragma unroll
        for (int u=0;u<4;++u) av[u] = p[u];
      } else {
        int b = am/400, s = am - b*400;
        const float* p;
        if (k0 < 256)      p = a0 + ((size_t)(b*100 + (s>>2)))*COND_ + k0;
        else if (k0 < 296) p = a1 + ((size_t)(b*400 + s))*SUB_ + (k0-256);
        else               p = a2 + ((size_t)(b*400 + s))*SUB_ + (k0-296);
        #pragma unroll
        for (int u=0;u<4;++u) av[u] = p[u];
      }
    }
    float bv[4];
    {
      int kB = kbase + bk;
      if constexpr (MODE==0){
        if (kB < 84){
          const float* p = Bm + (size_t)kB*256 + n0 + bn4;
          #pragma unroll
          for (int u=0;u<4;++u) bv[u] = p[u];
        } else { bv[0]=bv[1]=bv[2]=bv[3]=0.f; }
      } else if constexpr (MODE==4){
        int krow = (kB < 256) ? kB : kB + 40;
        const float* p = Bm + (size_t)krow*256 + n0 + bn4;
        #pragma unroll
        for (int u=0;u<4;++u) bv[u] = p[u];
      } else {
        const float* p = Bm + (size_t)kB*256 + n0 + bn4;
        #pragma unroll
        for (int u=0;u<4;++u) bv[u] = p[u];
      }
    }
    #pragma unroll
    for (int u=0;u<4;++u) As[akq+u][tid>>2] = av[u];
    #pragma unroll
    for (int u=0;u<4;++u) Bs[bk][bn4+u] = bv[u];
    __syncthreads();
    #pragma unroll
    for (int k = 0; k < 16; ++k){
      float a4[4], b4[4];
      #pragma unroll
      for (int i=0;i<4;++i) a4[i] = As[k][ty*4+i];
      #pragma unroll
      for (int j=0;j<4;++j) b4[j] = Bs[k][tx*4+j];
      #pragma unroll
      for (int i=0;i<4;++i)
        #pragma unroll
        for (int j=0;j<4;++j)
          acc[i][j] += a4[i]*b4[j];
    }
    __syncthreads();
  }
  #pragma unroll
  for (int i=0;i<4;++i){
    int m = m0 + ty*4 + i;
    #pragma unroll
    for (int j=0;j<4;++j){
      int n = n0 + tx*4 + j;
      float v = acc[i][j] + bias[n];
      if constexpr (MODE == 4){
        int b = m/400, s = m - b*400;
        C[((size_t)s*64 + b)*256 + n] = v;     // transposed [s][b][c]
      } else {
        C[(size_t)m*256 + n] = fast_tanh(v);
      }
    }
  }
}

// ---------------- persistent AR scan ----------------
// XCD-aware: cluster g = XCD pair {2g,2g+1} (round-robin heuristic).
// S1,G1 on XCD 2g; G2,G3 on 2g+1 -> tt2/h2/self-h intra-XCD (sc0/L2),
// h1/h3 cross (MALL). Dual-store + sticky escalation keeps correctness if
// placement differs.
__global__ __launch_bounds__(256, 1) void k_scan(
  const float* __restrict__ sd1_w, const float* __restrict__ sd2_w, const float* __restrict__ sd2_b,
  const float* __restrict__ g1_wi, const float* __restrict__ g1_bi, const float* __restrict__ g1_wh, const float* __restrict__ g1_bh,
  const float* __restrict__ g2_wi, const float* __restrict__ g2_bi, const float* __restrict__ g2_wh, const float* __restrict__ g2_bh,
  const float* __restrict__ g3_wi, const float* __restrict__ g3_bi, const float* __restrict__ g3_wh, const float* __restrict__ g3_bh,
  const float* __restrict__ out_w, const float* __restrict__ out_b,
  const float* __restrict__ tt1p,
  unsigned int* __restrict__ tt2i, unsigned int* __restrict__ tt2m,
  unsigned int* __restrict__ h1i,  unsigned int* __restrict__ h1m,
  unsigned int* __restrict__ h2i,  unsigned int* __restrict__ h2m,
  unsigned int* __restrict__ h3i,  unsigned int* __restrict__ h3m,
  float* __restrict__ out)
{
  __shared__ __align__(16) char smem[65536];
  int tid = threadIdx.x;
  int lane = tid & 63, wave = tid >> 6;
  int q = lane >> 4, nI = lane & 15;
  int bI = blockIdx.x;
  int xcd = bI & 7;
  int g = xcd >> 1, half = xcd & 1;
  int a = bI >> 3;
  int set = half*2 + (a >> 4);       // 0=S1 1=G1 2=G2 3=G3
  int sl = a & 15;
  int b0 = g*16;

  if (set == 0){
    // ===== S1: h3 -> prev -> tt1 -> tt2-slice =====
    char* outwF = smem;            // 24576
    char* sd1p0 = smem + 24576;    // 16384
    char* sd1p1 = smem + 40960;    // 4096
    char* sd2F  = smem + 45056;    // 8192
    char* stage = smem + 53248;    // 8192
    char* prevl = smem + 61440;    // 2304
    int col1 = sl*16 + nI;
    bool mallH3 = true;            // cross-XCD by design

    for (int t = wave; t < 24; t += 4){
      int nt = t >> 3, kk = t & 7;
      int c = nt*16 + nI;
      unsigned short v[8];
      #pragma unroll
      for (int j = 0; j < 8; ++j){
        int k = kk*32 + q*8 + j;
        v[j] = (c < 40) ? f2bf(out_w[(size_t)k*40 + c]) : (unsigned short)0;
      }
      *(short8*)(outwF + (t*64 + lane)*16) = *(short8*)v;
    }
    for (int t = wave; t < 16; t += 4){
      unsigned short v[8];
      #pragma unroll
      for (int j = 0; j < 8; ++j){
        int k = q*8 + j;
        v[j] = f2bf(sd1_w[(size_t)(256+k)*256 + t*16 + nI]);
      }
      *(short8*)(sd1p0 + (t*64 + lane)*16) = *(short8*)v;
    }
    {
      int nt = tid >> 4, ln = tid & 15;
      unsigned short v[8];
      #pragma unroll
      for (int j = 0; j < 8; ++j)
        v[j] = f2bf(sd1_w[(size_t)(256+32+j)*256 + nt*16 + ln]);
      *(short8*)(sd1p1 + tid*16) = *(short8*)v;
    }
    for (int t = wave; t < 8; t += 4){
      unsigned short v[8];
      #pragma unroll
      for (int j = 0; j < 8; ++j){
        int k = t*32 + q*8 + j;
        v[j] = f2bf(sd2_w[(size_t)k*256 + col1]);
      }
      *(short8*)(sd2F + (t*64 + lane)*16) = *(short8*)v;
    }
    for (int e = tid; e < 16*72; e += 256) *(unsigned short*)(prevl + e*2) = 0;
    float bout = 0.f;
    if (wave < 3){ int c = wave*16 + nI; if (c < 40) bout = out_b[c]; }
    float bsd2 = sd2_b[col1];
    __syncthreads();

    for (int s = 0; s <= STEPS_; ++s){
      float t1r[16];
      if (s < STEPS_){
        const float* tb = tt1p + ((size_t)s*64 + b0)*256;
        #pragma unroll
        for (int ii = 0; ii < 4; ++ii){
          int c = (wave*4 + ii)*16 + nI;
          #pragma unroll
          for (int i = 0; i < 4; ++i)
            t1r[ii*4+i] = tb[(q*4+i)*256 + c];
        }
      }
      float pv4[4] = {0.f,0.f,0.f,0.f};
      if (s > 0){
        int pb = (int)(((s+1)&1)*4 + g)*4096;
        unsigned int w8[8];
        poll_pair(h3i + pb, h3m + pb, tid*8, tid*8 + 2048, (unsigned)s, w8, mallH3);
        {
          int c0 = tid, c1 = tid + 256;
          int r0 = c0>>5, gc0 = c0&31, r1 = c1>>5, gc1 = c1&31;
          *(intx4*)(stage + (r0*32 + (gc0 ^ (r0 & 7)))*16) = (intx4){(int)w8[0],(int)w8[1],(int)w8[2],(int)w8[3]};
          *(intx4*)(stage + (r1*32 + (gc1 ^ (r1 & 7)))*16) = (intx4){(int)w8[4],(int)w8[5],(int)w8[6],(int)w8[7]};
        }
        __syncthreads();
        if (wave < 3){
          floatx4 acc = {0.f,0.f,0.f,0.f};
          #pragma unroll
          for (int kk = 0; kk < 8; ++kk){
            short8 av = *(const short8*)(stage + (nI*32 + ((kk*4+q) ^ (nI & 7)))*16);
            short8 bv = *(const short8*)(outwF + ((wave*8+kk)*64 + lane)*16);
            acc = mfma16(av, bv, acc);
          }
          int c = wave*16 + nI;
          #pragma unroll
          for (int i = 0; i < 4; ++i){
            int row = q*4 + i;
            float pv = (c < 40) ? fast_tanh(acc[i] + bout) : 0.f;
            *(unsigned short*)(prevl + (row*72 + c)*2) = f2bf(pv);
            pv4[i] = pv;
          }
        }
      }
      if (s == STEPS_){
        if (sl == 0 && wave < 3){
          int c = wave*16 + nI;
          if (c < 40){
            #pragma unroll
            for (int i = 0; i < 4; ++i)
              out[(size_t)(b0+q*4+i)*16000 + (size_t)(s-1)*40 + c] = pv4[i];
          }
        }
        break;
      }
      __syncthreads();
      // tt1 = tanh(tt1p[s] + prev @ sd1p) -> stage
      #pragma unroll
      for (int ii = 0; ii < 4; ++ii){
        int nt = wave*4 + ii;
        floatx4 acc = {0.f,0.f,0.f,0.f};
        short8 a0v = *(const short8*)(prevl + nI*144 + q*16);
        short8 b0v = *(const short8*)(sd1p0 + (nt*64 + lane)*16);
        acc = mfma16(a0v, b0v, acc);
        short8 a1v = *(const short8*)(prevl + nI*144 + 64 + q*16);
        short8 b1v = {0,0,0,0,0,0,0,0};
        if (q == 0) b1v = *(const short8*)(sd1p1 + (nt*16 + nI)*16);
        acc = mfma16(a1v, b1v, acc);
        int c = nt*16 + nI;
        #pragma unroll
        for (int i = 0; i < 4; ++i){
          int row = q*4 + i;
          float tv = fast_tanh(acc[i] + t1r[ii*4+i]);
          int gc = c >> 3;
          *(unsigned short*)(stage + (row*32 + (gc ^ (row & 7)))*16 + (c & 7)*2) = f2bf(tv);
        }
      }
      __syncthreads();
      if (wave == 0){
        floatx4 acc = {0.f,0.f,0.f,0.f};
        #pragma unroll
        for (int kk = 0; kk < 8; ++kk){
          short8 av = *(const short8*)(stage + (nI*32 + ((kk*4+q) ^ (nI & 7)))*16);
          short8 bv = *(const short8*)(sd2F + (kk*64 + lane)*16);
          acc = mfma16(av, bv, acc);
        }
        int pb = (int)((s&1)*4 + g)*4096;
        unsigned int pst = (unsigned int)(s+1) << 16;
        #pragma unroll
        for (int i = 0; i < 4; ++i){
          int row = q*4 + i;
          unsigned int v = pst | f2bf(fast_tanh(acc[i] + bsd2));
          st_dual(tt2i + pb + row*256 + col1, tt2m + pb + row*256 + col1, v);
        }
      }
      if (s > 0 && sl == 0 && wave < 3){
        int c = wave*16 + nI;
        if (c < 40){
          #pragma unroll
          for (int i = 0; i < 4; ++i)
            out[(size_t)(b0+q*4+i)*16000 + (size_t)(s-1)*40 + c] = pv4[i];
        }
      }
      // no end barrier: stage reuse gated by next h3 poll
    }
  } else {
    // ===== GRU set =====
    int gi_ = set - 1;
    const float* wi = (gi_==0) ? g1_wi : (gi_==1) ? g2_wi : g3_wi;
    const float* wh = (gi_==0) ? g1_wh : (gi_==1) ? g2_wh : g3_wh;
    const float* bi = (gi_==0) ? g1_bi : (gi_==1) ? g2_bi : g3_bi;
    const float* bh = (gi_==0) ? g1_bh : (gi_==1) ? g2_bh : g3_bh;
    unsigned int* hOi = (gi_==0) ? h1i : (gi_==1) ? h2i : h3i;
    unsigned int* hOm = (gi_==0) ? h1m : (gi_==1) ? h2m : h3m;
    const unsigned int* xBi = (gi_==0) ? tt2i : (gi_==1) ? h1i : h2i;
    const unsigned int* xBm = (gi_==0) ? tt2m : (gi_==1) ? h1m : h2m;
    bool mallH = false;                  // own-h always intra by design
    bool mallX = (gi_ == 1);             // h1 crosses the XCD pair; tt2/h2 intra
    char* wlds  = smem;          // 49152
    char* stage = smem + 49152;  // 16384: x chunks 0..31, h chunks 32..63 per row
    int hc0 = sl*16;
    // ex exchange aliased onto the h-half of `stage` (safe: h reads end before
    // the post-stage-x barrier; h-half rewrite is gated by the own-h poll).
    auto exb = [&](int v)->char*{ int b = v*4; return stage + (b>>9)*1024 + 512 + (b & 511); };

    for (int t = wave; t < 48; t += 4){
      unsigned short v[8];
      #pragma unroll
      for (int j = 0; j < 8; ++j){
        float w;
        if (t < 32){
          int k512 = (t & 15)*32 + q*8 + j;
          int col = ((t < 16) ? 0 : 256) + hc0 + nI;
          w = (k512 < 256) ? wi[(size_t)k512*768 + col] : wh[(size_t)(k512-256)*768 + col];
        } else if (t < 40){
          int k = (t-32)*32 + q*8 + j;
          w = wi[(size_t)k*768 + 512 + hc0 + nI];
        } else {
          int k = (t-40)*32 + q*8 + j;
          w = wh[(size_t)k*768 + 512 + hc0 + nI];
        }
        v[j] = f2bf(w);
      }
      *(short8*)(wlds + (t*64 + lane)*16) = *(short8*)v;
    }
    float br = 0.f, bz = 0.f, bin = 0.f, bhn = 0.f;
    if (wave == 0){
      int cg = hc0 + nI;
      br  = bi[cg] + bh[cg];
      bz  = bi[256+cg] + bh[256+cg];
      bin = bi[512+cg];
      bhn = bh[512+cg];
    }
    floatx4 hst = {0.f,0.f,0.f,0.f};
    __syncthreads();

    for (int s = 0; s < STEPS_; ++s){
      floatx4 acc = {0.f,0.f,0.f,0.f};
      // --- phase A: own h(s-1) (intra) + h-half MFMAs ---
      if (s > 0){
        int pb = (int)(((s+1)&1)*4 + g)*4096;
        unsigned int w8[8];
        poll_pair(hOi + pb, hOm + pb, tid*8, tid*8 + 2048, (unsigned)s, w8, mallH);
        {
          int c0 = tid, c1 = tid + 256;
          int r0 = c0>>5, gc0 = c0&31, r1 = c1>>5, gc1 = c1&31;
          *(intx4*)(stage + (r0*64 + ((32+gc0) ^ (r0 & 7)))*16) = (intx4){(int)w8[0],(int)w8[1],(int)w8[2],(int)w8[3]};
          *(intx4*)(stage + (r1*64 + ((32+gc1) ^ (r1 & 7)))*16) = (intx4){(int)w8[4],(int)w8[5],(int)w8[6],(int)w8[7]};
        }
        __syncthreads();
        if (wave < 2){
          int tb = wave*16;
          #pragma unroll
          for (int kt = 8; kt < 16; ++kt){
            short8 av = *(const short8*)(stage + (nI*64 + ((kt*4+q) ^ (nI & 7)))*16);
            short8 bv = *(const short8*)(wlds + ((tb+kt)*64 + lane)*16);
            acc = mfma16(av, bv, acc);
          }
        } else if (wave == 3){
          #pragma unroll
          for (int kt = 0; kt < 8; ++kt){
            short8 av = *(const short8*)(stage + (nI*64 + ((32 + kt*4+q) ^ (nI & 7)))*16);
            short8 bv = *(const short8*)(wlds + ((40+kt)*64 + lane)*16);
            acc = mfma16(av, bv, acc);
          }
        }
      }
      // --- phase B: x(s) + x-half MFMAs ---
      {
        int pb = (int)((s&1)*4 + g)*4096;
        unsigned int w8[8];
        poll_pair(xBi + pb, xBm + pb, tid*8, tid*8 + 2048, (unsigned)(s+1), w8, mallX);
        int c0 = tid, c1 = tid + 256;
        int r0 = c0>>5, gc0 = c0&31, r1 = c1>>5, gc1 = c1&31;
        *(intx4*)(stage + (r0*64 + (gc0 ^ (r0 & 7)))*16) = (intx4){(int)w8[0],(int)w8[1],(int)w8[2],(int)w8[3]};
        *(intx4*)(stage + (r1*64 + (gc1 ^ (r1 & 7)))*16) = (intx4){(int)w8[4],(int)w8[5],(int)w8[6],(int)w8[7]};
      }
      __syncthreads();
      if (wave < 2){
        int tb = wave*16;
        #pragma unroll
        for (int kt = 0; kt < 8; ++kt){
          short8 av = *(const short8*)(stage + (nI*64 + ((kt*4+q) ^ (nI & 7)))*16);
          short8 bv = *(const short8*)(wlds + ((tb+kt)*64 + lane)*16);
          acc = mfma16(av, bv, acc);
        }
      } else if (wave == 2){
        #pragma unroll
        for (int kt = 0; kt < 8; ++kt){
          short8 av = *(const short8*)(stage + (nI*64 + ((kt*4+q) ^ (nI & 7)))*16);
          short8 bv = *(const short8*)(wlds + ((32+kt)*64 + lane)*16);
          acc = mfma16(av, bv, acc);
        }
      }
      if (wave >= 1){
        int vb = (wave-1)*256;
        #pragma unroll
        for (int i = 0; i < 4; ++i)
          *(float*)exb(vb + (q*4+i)*16 + nI) = acc[i];
      }
      __syncthreads();
      if (wave == 0){
        int pb = (int)((s&1)*4 + g)*4096;
        unsigned int pst = (unsigned int)(s+1) << 16;
        #pragma unroll
        for (int i = 0; i < 4; ++i){
          int row = q*4 + i;
          float zr  = *(float*)exb(0*256 + row*16 + nI);
          float inr = *(float*)exb(1*256 + row*16 + nI);
          float hnr = *(float*)exb(2*256 + row*16 + nI);
          float rv = fast_sigm(acc[i] + br);
          float zv = fast_sigm(zr + bz);
          float nv = fast_tanh(inr + bin + rv*(hnr + bhn));
          float hv = (1.f - zv)*nv + zv*hst[i];
          hst[i] = hv;
          unsigned int v = pst | f2bf(hv);
          st_dual(hOi + pb + row*256 + hc0 + nI, hOm + pb + row*256 + hc0 + nI, v);
          if (s == STEPS_-1)
            out[1024000 + gi_*16384 + (size_t)(b0+row)*256 + hc0 + nI] = hv;
        }
      }
      // no end barrier: stage/ex reuse gated by next own-h poll
    }
  }
}

extern "C" void kernel_launch(void* const* d_in, const int* in_sizes, int n_in,
                              void* d_out, int out_size, void* d_ws, size_t ws_size,
                              hipStream_t stream){
  (void)in_sizes; (void)n_in; (void)out_size; (void)ws_size;
  const float* features = (const float*)d_in[0];
  const int*   period   = (const int*)d_in[1];
  const float* rshift   = (const float*)d_in[3];
  const float* pembed   = (const float*)d_in[4];
  const float* fd1_w = (const float*)d_in[5];  const float* fd1_b = (const float*)d_in[6];
  const float* c1w   = (const float*)d_in[7];  const float* c1b   = (const float*)d_in[8];
  const float* c2w   = (const float*)d_in[9];  const float* c2b   = (const float*)d_in[10];
  const float* fd2_w = (const float*)d_in[11]; const float* fd2_b = (const float*)d_in[12];
  const float* sd1_w = (const float*)d_in[13]; const float* sd1_b = (const float*)d_in[14];
  const float* sd2_w = (const float*)d_in[15]; const float* sd2_b = (const float*)d_in[16];
  const float* g1_wi = (const float*)d_in[17]; const float* g1_bi = (const float*)d_in[18];
  const float* g1_wh = (const float*)d_in[19]; const float* g1_bh = (const float*)d_in[20];
  const float* g2_wi = (const float*)d_in[21]; const float* g2_bi = (const float*)d_in[22];
  const float* g2_wh = (const float*)d_in[23]; const float* g2_bh = (const float*)d_in[24];
  const float* g3_wi = (const float*)d_in[25]; const float* g3_bi = (const float*)d_in[26];
  const float* g3_wh = (const float*)d_in[27]; const float* g3_bh = (const float*)d_in[28];
  const float* out_w = (const float*)d_in[29]; const float* out_b = (const float*)d_in[30];

  char* ws = (char*)d_ws;
  size_t off = 0;
  auto alloc = [&](size_t bytes)->char*{
    char* p = ws + off; off += (bytes + 255) & ~(size_t)255; return p;
  };
  unsigned int* tt2i = (unsigned int*)alloc(32768*4);
  unsigned int* tt2m = (unsigned int*)alloc(32768*4);
  unsigned int* h1iB = (unsigned int*)alloc(32768*4);
  unsigned int* h1mB = (unsigned int*)alloc(32768*4);
  unsigned int* h2iB = (unsigned int*)alloc(32768*4);
  unsigned int* h2mB = (unsigned int*)alloc(32768*4);
  unsigned int* h3iB = (unsigned int*)alloc(32768*4);
  unsigned int* h3mB = (unsigned int*)alloc(32768*4);
  float* tt1p = (float*)alloc((size_t)B_*STEPS_*COND_*4);   // [s][b][c]
  float* pr   = (float*)alloc((size_t)B_*STEPS_*SUB_*4);
  float* pi   = (float*)alloc((size_t)B_*STEPS_*SUB_*4);
  float* tbuf = (float*)alloc((size_t)B_*T_*COND_*4);
  float* x1   = (float*)alloc((size_t)B_*102*COND_*4);
  float* x2   = (float*)alloc((size_t)B_*100*COND_*4);
  float* cb   = (float*)alloc((size_t)B_*100*COND_*4);
  float* w1t  = (float*)alloc((size_t)768*256*4);
  float* w2t  = (float*)alloc((size_t)768*256*4);

  k_phase<<<64, 256, 0, stream>>>(period, rshift, pr, pi);
  k_prep<<<256, 256, 0, stream>>>(c1w, c2w, w1t, w2t);
  k_gemm<0><<<dim3(104,4), 256, 0, stream>>>(features, pembed, nullptr, period, fd1_w, fd1_b, tbuf);
  k_gemm<1><<<dim3(102,4), 256, 0, stream>>>(tbuf, nullptr, nullptr, nullptr, w1t, c1b, x1);
  k_gemm<2><<<dim3(100,4), 256, 0, stream>>>(x1, nullptr, nullptr, nullptr, w2t, c2b, x2);
  k_gemm<3><<<dim3(100,4), 256, 0, stream>>>(x2, nullptr, nullptr, nullptr, fd2_w, fd2_b, cb);
  k_gemm<4><<<dim3(400,4), 256, 0, stream>>>(cb, pr, pi, nullptr, sd1_w, sd1_b, tt1p);
  k_scan<<<256, 256, 0, stream>>>(sd1_w, sd2_w, sd2_b,
                                  g1_wi, g1_bi, g1_wh, g1_bh,
                                  g2_wi, g2_bi, g2_wh, g2_bh,
                                  g3_wi, g3_bi, g3_wh, g3_bh,
                                  out_w, out_b, tt1p,
                                  tt2i, tt2m, h1iB, h1mB, h2iB, h2mB, h3iB, h3mB,
                                  (float*)d_out);
}

// Round 8
// 13697.116 us; speedup vs baseline: 10.6742x; 10.6742x over previous
//
#include <hip/hip_runtime.h>
#include <hip/hip_bf16.h>
#include <math.h>

#define B_ 64
#define T_ 104
#define FEAT_ 20
#define PEMB_ 64
#define COND_ 256
#define SUB_ 40
#define NBF_ 100
#define STEPS_ 400

typedef short short8 __attribute__((ext_vector_type(8)));
typedef float floatx4 __attribute__((ext_vector_type(4)));
typedef int intx4 __attribute__((ext_vector_type(4)));

__device__ inline unsigned short f2bf(float x){
  unsigned int u = __float_as_uint(x);
  unsigned int r = (u + 0x7fffu + ((u >> 16) & 1u)) >> 16;
  return (unsigned short)r;
}
__device__ inline float fast_tanh(float x){
  float e = __expf(2.f*x);
  return 1.f - 2.f*__builtin_amdgcn_rcpf(e + 1.f);
}
__device__ inline float fast_sigm(float x){
  return __builtin_amdgcn_rcpf(1.f + __expf(-x));
}
__device__ inline floatx4 mfma16(short8 a, short8 b, floatx4 c){
  return __builtin_amdgcn_mfma_f32_16x16x32_bf16(a, b, c, 0, 0, 0);
}
__device__ inline int get_xcd(){
  unsigned int x;
  asm volatile("s_getreg_b32 %0, hwreg(20, 0, 32)" : "=s"(x));
  return (int)(x & 7u);
}
// producer: plain store -> local (shared) L2; agent store -> MALL backup copy
__device__ inline void st_pair(unsigned int* pl, unsigned int* pm, unsigned int v){
  asm volatile("global_store_dword %0, %1, off" :: "v"(pl), "v"(v) : "memory");
  asm volatile("global_store_dword %0, %1, off sc0 sc1" :: "v"(pm), "v"(v) : "memory");
}

// One 8-u32 (32B) stamped chunk: try a read, check all stamps == tgt.
__device__ inline bool try8(const unsigned int* p, bool mall, unsigned int tgt, unsigned int* w){
  intx4 a0, a1;
  if (!mall){
    asm volatile("global_load_dwordx4 %0, %2, off sc0\n\t"
                 "global_load_dwordx4 %1, %2, off offset:16 sc0\n\t"
                 "s_waitcnt vmcnt(0)"
                 : "=&v"(a0), "=&v"(a1) : "v"(p) : "memory");
  } else {
    asm volatile("global_load_dwordx4 %0, %2, off sc0 sc1\n\t"
                 "global_load_dwordx4 %1, %2, off offset:16 sc0 sc1\n\t"
                 "s_waitcnt vmcnt(0)"
                 : "=&v"(a0), "=&v"(a1) : "v"(p) : "memory");
  }
  unsigned int m = (((unsigned)a0.x>>16)^tgt) | (((unsigned)a0.y>>16)^tgt)
                 | (((unsigned)a0.z>>16)^tgt) | (((unsigned)a0.w>>16)^tgt)
                 | (((unsigned)a1.x>>16)^tgt) | (((unsigned)a1.y>>16)^tgt)
                 | (((unsigned)a1.z>>16)^tgt) | (((unsigned)a1.w>>16)^tgt);
  if (m) return false;
  w[0]=((unsigned)a0.x&0xFFFFu)|((unsigned)a0.y<<16);
  w[1]=((unsigned)a0.z&0xFFFFu)|((unsigned)a0.w<<16);
  w[2]=((unsigned)a1.x&0xFFFFu)|((unsigned)a1.y<<16);
  w[3]=((unsigned)a1.z&0xFFFFu)|((unsigned)a1.w<<16);
  return true;
}
// Poll local-L2 copy; sticky-escalate to MALL copy if it never arrives.
__device__ inline void poll8(const unsigned int* pl, const unsigned int* pm,
                             unsigned int tgt, unsigned int* w, bool& mall){
  if (!mall){
    int it = 0;
    for(;;){
      if (try8(pl, false, tgt, w)) return;
      if (++it > 512){ mall = true; break; }
    }
  }
  while (!try8(pm, true, tgt, w)) __builtin_amdgcn_s_sleep(1);
}

// ---------------- phase embedding ----------------
__global__ void k_phase(const int* __restrict__ period, const float* __restrict__ rshift,
                        float* __restrict__ pr, float* __restrict__ pi){
  int b = blockIdx.x;
  __shared__ float cumf[NBF_], w0f[NBF_];
  if (threadIdx.x == 0){
    double acc = 2.0*M_PI*(double)rshift[b];
    for (int f = 0; f < NBF_; ++f){
      double w0 = 2.0*M_PI/(double)period[b*T_ + 3 + f];
      cumf[f] = (float)fmod(acc, 2.0*M_PI);
      w0f[f] = (float)w0;
      acc += 160.0*w0;
    }
  }
  __syncthreads();
  for (int e = threadIdx.x; e < NBF_*160; e += blockDim.x){
    int f = e/160, j = e - f*160;
    float ph = cumf[f] + w0f[f]*(float)j;
    int s = f*4 + j/40, u = j%40;
    pr[((size_t)b*STEPS_ + s)*SUB_ + u] = cosf(ph);
    pi[((size_t)b*STEPS_ + s)*SUB_ + u] = sinf(ph);
  }
}

// ---------------- prep: zero slot counters, transpose conv weights ----------------
__global__ void k_prep(const float* __restrict__ c1w, const float* __restrict__ c2w,
                       float* __restrict__ w1t, float* __restrict__ w2t,
                       unsigned int* __restrict__ ctr){
  size_t tid = (size_t)blockIdx.x*blockDim.x + threadIdx.x;
  size_t nt = (size_t)gridDim.x*blockDim.x;
  for (size_t e = tid; e < 128; e += nt) ctr[e] = 0u;
  for (size_t e = tid; e < 768u*256u; e += nt){
    int kk = (int)(e >> 8), o = (int)(e & 255);
    int i = kk & 255, kc = kk >> 8;
    w1t[e] = c1w[(size_t)o*768 + i*3 + kc];
    w2t[e] = c2w[(size_t)o*768 + i*3 + kc];
  }
}

// ---------------- generic fp32 tiled GEMM (M x K x 256) ----------------
template<int MODE>
__global__ __launch_bounds__(256) void k_gemm(
    const float* __restrict__ a0, const float* __restrict__ a1, const float* __restrict__ a2,
    const int* __restrict__ ip,
    const float* __restrict__ Bm, const float* __restrict__ bias, float* __restrict__ C)
{
  constexpr int KT = (MODE==0) ? 6 : (MODE==1||MODE==2) ? 48 : (MODE==3) ? 16 : 21;
  __shared__ float As[16][68];
  __shared__ float Bs[16][68];
  int tid = threadIdx.x;
  int m0 = blockIdx.x*64, n0 = blockIdx.y*64;
  int tx = tid & 15, ty = tid >> 4;
  float acc[4][4] = {};
  int am = m0 + (tid >> 2);
  int akq = (tid & 3)*4;
  int bk = tid >> 4;
  int bn4 = (tid & 15)*4;

  for (int kt = 0; kt < KT; ++kt){
    int kbase = kt*16;
    float av[4];
    {
      int k0 = kbase + akq;
      if constexpr (MODE==0){
        if (k0 < 20){
          const float* p = a0 + (size_t)am*FEAT_ + k0;
          #pragma unroll
          for (int u=0;u<4;++u) av[u] = p[u];
        } else if (k0 < 84){
          const float* p = a1 + (size_t)ip[am]*PEMB_ + (k0-20);
          #pragma unroll
          for (int u=0;u<4;++u) av[u] = p[u];
        } else { av[0]=av[1]=av[2]=av[3]=0.f; }
      } else if constexpr (MODE==1){
        int b = am/102, t2 = am - b*102;
        int i = k0 & 255, kc = k0 >> 8;
        const float* p = a0 + ((size_t)(b*T_ + t2 + kc))*COND_ + i;
        #pragma unroll
        for (int u=0;u<4;++u) av[u] = p[u];
      } else if constexpr (MODE==2){
        int b = am/100, t2 = am - b*100;
        int i = k0 & 255, kc = k0 >> 8;
        const float* p = a0 + ((size_t)(b*102 + t2 + kc))*COND_ + i;
        #pragma unroll
        for (int u=0;u<4;++u) av[u] = p[u];
      } else if constexpr (MODE==3){
        const float* p = a0 + (size_t)am*COND_ + k0;
        #pragma unroll
        for (int u=0;u<4;++u) av[u] = p[u];
      } else {
        int b = am/400, s = am - b*400;
        const float* p;
        if (k0 < 256)      p = a0 + ((size_t)(b*100 + (s>>2)))*COND_ + k0;
        else if (k0 < 296) p = a1 + ((size_t)(b*400 + s))*SUB_ + (k0-256);
        else               p = a2 + ((size_t)(b*400 + s))*SUB_ + (k0-296);
        #pragma unroll
        for (int u=0;u<4;++u) av[u] = p[u];
      }
    }
    float bv[4];
    {
      int kB = kbase + bk;
      if constexpr (MODE==0){
        if (kB < 84){
          const float* p = Bm + (size_t)kB*256 + n0 + bn4;
          #pragma unroll
          for (int u=0;u<4;++u) bv[u] = p[u];
        } else { bv[0]=bv[1]=bv[2]=bv[3]=0.f; }
      } else if constexpr (MODE==4){
        int krow = (kB < 256) ? kB : kB + 40;
        const float* p = Bm + (size_t)krow*256 + n0 + bn4;
        #pragma unroll
        for (int u=0;u<4;++u) bv[u] = p[u];
      } else {
        const float* p = Bm + (size_t)kB*256 + n0 + bn4;
        #pragma unroll
        for (int u=0;u<4;++u) bv[u] = p[u];
      }
    }
    #pragma unroll
    for (int u=0;u<4;++u) As[akq+u][tid>>2] = av[u];
    #pragma unroll
    for (int u=0;u<4;++u) Bs[bk][bn4+u] = bv[u];
    __syncthreads();
    #pragma unroll
    for (int k = 0; k < 16; ++k){
      float a4[4], b4[4];
      #pragma unroll
      for (int i=0;i<4;++i) a4[i] = As[k][ty*4+i];
      #pragma unroll
      for (int j=0;j<4;++j) b4[j] = Bs[k][tx*4+j];
      #pragma unroll
      for (int i=0;i<4;++i)
        #pragma unroll
        for (int j=0;j<4;++j)
          acc[i][j] += a4[i]*b4[j];
    }
    __syncthreads();
  }
  #pragma unroll
  for (int i=0;i<4;++i){
    int m = m0 + ty*4 + i;
    #pragma unroll
    for (int j=0;j<4;++j){
      int n = n0 + tx*4 + j;
      float v = acc[i][j] + bias[n];
      if constexpr (MODE == 4){
        int b = m/400, s = m - b*400;
        C[((size_t)s*64 + b)*256 + n] = v;     // transposed [s][b][c]
      } else {
        C[(size_t)m*256 + n] = fast_tanh(v);
      }
    }
  }
}

// ---------------- persistent AR scan ----------------
// 8 clusters, one PER PHYSICAL XCD (runtime XCC_ID). 512 blocks x 64KB LDS
// -> exactly 2 blocks/CU -> exactly 64 blocks/XCD (capacity-guaranteed).
// Roles via per-XCD atomic slot: 16 S1 + 16 G1 + 16 G2 + 16 G3, 8 batch rows.
// All handoffs are same-L2 (plain store -> sc0 load); MALL dual-copy as a
// sticky fallback (threshold 512) if the cache model is wrong.
__global__ __launch_bounds__(256, 1) void k_scan(
  const float* __restrict__ sd1_w, const float* __restrict__ sd2_w, const float* __restrict__ sd2_b,
  const float* __restrict__ g1_wi, const float* __restrict__ g1_bi, const float* __restrict__ g1_wh, const float* __restrict__ g1_bh,
  const float* __restrict__ g2_wi, const float* __restrict__ g2_bi, const float* __restrict__ g2_wh, const float* __restrict__ g2_bh,
  const float* __restrict__ g3_wi, const float* __restrict__ g3_bi, const float* __restrict__ g3_wh, const float* __restrict__ g3_bh,
  const float* __restrict__ out_w, const float* __restrict__ out_b,
  const float* __restrict__ tt1p, unsigned int* __restrict__ ctr,
  unsigned int* __restrict__ tt2l, unsigned int* __restrict__ tt2m,
  unsigned int* __restrict__ h1l,  unsigned int* __restrict__ h1m,
  unsigned int* __restrict__ h2l,  unsigned int* __restrict__ h2m,
  unsigned int* __restrict__ h3l,  unsigned int* __restrict__ h3m,
  float* __restrict__ out)
{
  __shared__ __align__(16) char smem[65536];
  int tid = threadIdx.x;
  int lane = tid & 63, wave = tid >> 6;
  int q = lane >> 4, nI = lane & 15;

  __shared__ int sXcd, sSlot;
  if (tid == 0){
    int x = get_xcd();
    sXcd = x;
    sSlot = (int)__hip_atomic_fetch_add(ctr + x*16, 1u, __ATOMIC_RELAXED, __HIP_MEMORY_SCOPE_AGENT);
  }
  __syncthreads();
  int g = sXcd, slot = sSlot;
  if (slot >= 64) return;
  int set = slot >> 4, sl = slot & 15;
  int b0 = g*8;

  if (set == 0){
    // ===== S1: h3 -> prev -> tt1 -> tt2-slice (M=8) =====
    char* outwF = smem;            // 24576
    char* sd1p0 = smem + 24576;    // 16384
    char* sd1p1 = smem + 40960;    // 4096
    char* sd2F  = smem + 45056;    // 8192
    char* stage = smem + 53248;    // 8192 (16r x 32c; rows 8..15 garbage ok)
    char* prevl = smem + 61440;    // 2304
    int col1 = sl*16 + nI;
    bool mallH3 = false;

    for (int t = wave; t < 24; t += 4){
      int nt = t >> 3, kk = t & 7;
      int c = nt*16 + nI;
      unsigned short v[8];
      #pragma unroll
      for (int j = 0; j < 8; ++j){
        int k = kk*32 + q*8 + j;
        v[j] = (c < 40) ? f2bf(out_w[(size_t)k*40 + c]) : (unsigned short)0;
      }
      *(short8*)(outwF + (t*64 + lane)*16) = *(short8*)v;
    }
    for (int t = wave; t < 16; t += 4){
      unsigned short v[8];
      #pragma unroll
      for (int j = 0; j < 8; ++j){
        int k = q*8 + j;
        v[j] = f2bf(sd1_w[(size_t)(256+k)*256 + t*16 + nI]);
      }
      *(short8*)(sd1p0 + (t*64 + lane)*16) = *(short8*)v;
    }
    {
      int nt = tid >> 4, ln = tid & 15;
      unsigned short v[8];
      #pragma unroll
      for (int j = 0; j < 8; ++j)
        v[j] = f2bf(sd1_w[(size_t)(256+32+j)*256 + nt*16 + ln]);
      *(short8*)(sd1p1 + tid*16) = *(short8*)v;
    }
    for (int t = wave; t < 8; t += 4){
      unsigned short v[8];
      #pragma unroll
      for (int j = 0; j < 8; ++j){
        int k = t*32 + q*8 + j;
        v[j] = f2bf(sd2_w[(size_t)k*256 + col1]);
      }
      *(short8*)(sd2F + (t*64 + lane)*16) = *(short8*)v;
    }
    for (int e = tid; e < 16*72; e += 256) *(unsigned short*)(prevl + e*2) = 0;
    float bout = 0.f;
    if (wave < 3){ int c = wave*16 + nI; if (c < 40) bout = out_b[c]; }
    float bsd2 = sd2_b[col1];
    __syncthreads();

    for (int s = 0; s <= STEPS_; ++s){
      // prefetch tt1p slice (rows 0..7) into regs; overlaps the h3 poll
      float t1r[16];
      if (s < STEPS_ && q < 2){
        const float* tb = tt1p + ((size_t)s*64 + b0)*256;
        #pragma unroll
        for (int ii = 0; ii < 4; ++ii){
          int c = (wave*4 + ii)*16 + nI;
          #pragma unroll
          for (int i = 0; i < 4; ++i)
            t1r[ii*4+i] = tb[(q*4+i)*256 + c];
        }
      }
      float pv4[4] = {0.f,0.f,0.f,0.f};
      if (s > 0){
        int pb = (((s+1)&1)*8 + g)*2048 + tid*8;
        unsigned int w4[4];
        poll8(h3l + pb, h3m + pb, (unsigned)s, w4, mallH3);
        int row = tid >> 5, gc = tid & 31;
        *(intx4*)(stage + (row*32 + (gc ^ (row & 7)))*16) = *(intx4*)w4;
        __syncthreads();
        if (wave < 3){
          floatx4 acc = {0.f,0.f,0.f,0.f};
          #pragma unroll
          for (int kk = 0; kk < 8; ++kk){
            short8 av = *(const short8*)(stage + (nI*32 + ((kk*4+q) ^ (nI & 7)))*16);
            short8 bv = *(const short8*)(outwF + ((wave*8+kk)*64 + lane)*16);
            acc = mfma16(av, bv, acc);
          }
          int c = wave*16 + nI;
          if (q < 2){
            #pragma unroll
            for (int i = 0; i < 4; ++i){
              int row = q*4 + i;
              float pv = (c < 40) ? fast_tanh(acc[i] + bout) : 0.f;
              *(unsigned short*)(prevl + (row*72 + c)*2) = f2bf(pv);
              pv4[i] = pv;
            }
          }
        }
      }
      if (s == STEPS_){
        if (sl == 0 && wave < 3 && q < 2){
          int c = wave*16 + nI;
          if (c < 40){
            #pragma unroll
            for (int i = 0; i < 4; ++i)
              out[(size_t)(b0+q*4+i)*16000 + (size_t)(s-1)*40 + c] = pv4[i];
          }
        }
        break;
      }
      __syncthreads();
      // tt1 = tanh(tt1p[s] + prev @ sd1p) -> stage rows 0..7 (replicated cols)
      #pragma unroll
      for (int ii = 0; ii < 4; ++ii){
        int nt = wave*4 + ii;
        floatx4 acc = {0.f,0.f,0.f,0.f};
        short8 a0v = *(const short8*)(prevl + nI*144 + q*16);
        short8 b0v = *(const short8*)(sd1p0 + (nt*64 + lane)*16);
        acc = mfma16(a0v, b0v, acc);
        short8 a1v = *(const short8*)(prevl + nI*144 + 64 + q*16);
        short8 b1v = {0,0,0,0,0,0,0,0};
        if (q == 0) b1v = *(const short8*)(sd1p1 + (nt*16 + nI)*16);
        acc = mfma16(a1v, b1v, acc);
        int c = nt*16 + nI;
        if (q < 2){
          #pragma unroll
          for (int i = 0; i < 4; ++i){
            int row = q*4 + i;
            float tv = fast_tanh(acc[i] + t1r[ii*4+i]);
            int gc = c >> 3;
            *(unsigned short*)(stage + (row*32 + (gc ^ (row & 7)))*16 + (c & 7)*2) = f2bf(tv);
          }
        }
      }
      __syncthreads();
      if (wave == 0){
        floatx4 acc = {0.f,0.f,0.f,0.f};
        #pragma unroll
        for (int kk = 0; kk < 8; ++kk){
          short8 av = *(const short8*)(stage + (nI*32 + ((kk*4+q) ^ (nI & 7)))*16);
          short8 bv = *(const short8*)(sd2F + (kk*64 + lane)*16);
          acc = mfma16(av, bv, acc);
        }
        if (q < 2){
          int pb = ((s&1)*8 + g)*2048;
          unsigned int pst = (unsigned int)(s+1) << 16;
          #pragma unroll
          for (int i = 0; i < 4; ++i){
            int row = q*4 + i;
            unsigned int v = pst | f2bf(fast_tanh(acc[i] + bsd2));
            st_pair(tt2l + pb + row*256 + col1, tt2m + pb + row*256 + col1, v);
          }
        }
      }
      if (s > 0 && sl == 0 && wave < 3 && q < 2){
        int c = wave*16 + nI;
        if (c < 40){
          #pragma unroll
          for (int i = 0; i < 4; ++i)
            out[(size_t)(b0+q*4+i)*16000 + (size_t)(s-1)*40 + c] = pv4[i];
        }
      }
      // no loop-end barrier: stage reuse gated by the next h3 poll (pipeline depth)
    }
  } else {
    // ===== GRU set (set-1 = GRU index), M=8 =====
    int gi_ = set - 1;
    const float* wi = (gi_==0) ? g1_wi : (gi_==1) ? g2_wi : g3_wi;
    const float* wh = (gi_==0) ? g1_wh : (gi_==1) ? g2_wh : g3_wh;
    const float* bi = (gi_==0) ? g1_bi : (gi_==1) ? g2_bi : g3_bi;
    const float* bh = (gi_==0) ? g1_bh : (gi_==1) ? g2_bh : g3_bh;
    unsigned int* hOl = (gi_==0) ? h1l : (gi_==1) ? h2l : h3l;
    unsigned int* hOm = (gi_==0) ? h1m : (gi_==1) ? h2m : h3m;
    const unsigned int* xBl = (gi_==0) ? tt2l : (gi_==1) ? h1l : h2l;
    const unsigned int* xBm = (gi_==0) ? tt2m : (gi_==1) ? h1m : h2m;
    bool mallA = false, mallB = false;
    char* wlds  = smem;          // 49152: tiles 0..15 r, 16..31 z, 32..39 i_n, 40..47 h_n
    char* stage = smem + 49152;  // 16384: rows 0..7 = x|h chunks; rows 8..15 double as ex
    float* ex = (float*)(stage + 8192);
    int hc0 = sl*16;

    for (int t = wave; t < 48; t += 4){
      unsigned short v[8];
      #pragma unroll
      for (int j = 0; j < 8; ++j){
        float w;
        if (t < 32){
          int k512 = (t & 15)*32 + q*8 + j;
          int col = ((t < 16) ? 0 : 256) + hc0 + nI;
          w = (k512 < 256) ? wi[(size_t)k512*768 + col] : wh[(size_t)(k512-256)*768 + col];
        } else if (t < 40){
          int k = (t-32)*32 + q*8 + j;
          w = wi[(size_t)k*768 + 512 + hc0 + nI];
        } else {
          int k = (t-40)*32 + q*8 + j;
          w = wh[(size_t)k*768 + 512 + hc0 + nI];
        }
        v[j] = f2bf(w);
      }
      *(short8*)(wlds + (t*64 + lane)*16) = *(short8*)v;
    }
    float br = 0.f, bz = 0.f, bin = 0.f, bhn = 0.f;
    if (wave == 0){
      int cg = hc0 + nI;
      br  = bi[cg] + bh[cg];
      bz  = bi[256+cg] + bh[256+cg];
      bin = bi[512+cg];
      bhn = bh[512+cg];
    }
    floatx4 hst = {0.f,0.f,0.f,0.f};
    __syncthreads();

    for (int s = 0; s < STEPS_; ++s){
      floatx4 acc = {0.f,0.f,0.f,0.f};
      // --- phase A: own h(s-1) gather (same-L2) + h-half MFMAs ---
      if (s > 0){
        int pb = (((s+1)&1)*8 + g)*2048 + tid*8;
        unsigned int w4[4];
        poll8(hOl + pb, hOm + pb, (unsigned)s, w4, mallA);
        int row = tid >> 5, gc = tid & 31;
        *(intx4*)(stage + (row*64 + ((32+gc) ^ (row & 7)))*16) = *(intx4*)w4;
        __syncthreads();
        if (wave < 2){
          int tb = wave*16;
          #pragma unroll
          for (int kt = 8; kt < 16; ++kt){
            short8 av = *(const short8*)(stage + (nI*64 + ((kt*4+q) ^ (nI & 7)))*16);
            short8 bv = *(const short8*)(wlds + ((tb+kt)*64 + lane)*16);
            acc = mfma16(av, bv, acc);
          }
        } else if (wave == 3){
          #pragma unroll
          for (int kt = 0; kt < 8; ++kt){
            short8 av = *(const short8*)(stage + (nI*64 + ((32 + kt*4+q) ^ (nI & 7)))*16);
            short8 bv = *(const short8*)(wlds + ((40+kt)*64 + lane)*16);
            acc = mfma16(av, bv, acc);
          }
        }
      }
      // --- phase B: x(s) gather (same-L2) + x-half MFMAs ---
      {
        int pb = ((s&1)*8 + g)*2048 + tid*8;
        unsigned int w4[4];
        poll8(xBl + pb, xBm + pb, (unsigned)(s+1), w4, mallB);
        int row = tid >> 5, gc = tid & 31;
        *(intx4*)(stage + (row*64 + (gc ^ (row & 7)))*16) = *(intx4*)w4;
      }
      __syncthreads();
      if (wave < 2){
        int tb = wave*16;
        #pragma unroll
        for (int kt = 0; kt < 8; ++kt){
          short8 av = *(const short8*)(stage + (nI*64 + ((kt*4+q) ^ (nI & 7)))*16);
          short8 bv = *(const short8*)(wlds + ((tb+kt)*64 + lane)*16);
          acc = mfma16(av, bv, acc);
        }
      } else if (wave == 2){
        #pragma unroll
        for (int kt = 0; kt < 8; ++kt){
          short8 av = *(const short8*)(stage + (nI*64 + ((kt*4+q) ^ (nI & 7)))*16);
          short8 bv = *(const short8*)(wlds + ((32+kt)*64 + lane)*16);
          acc = mfma16(av, bv, acc);
        }
      }
      if (wave >= 1){
        #pragma unroll
        for (int i = 0; i < 4; ++i)
          ex[(wave-1)*256 + (q*4+i)*16 + nI] = acc[i];
      }
      __syncthreads();
      if (wave == 0){
        int pb = ((s&1)*8 + g)*2048;
        unsigned int pst = (unsigned int)(s+1) << 16;
        if (q < 2){
          #pragma unroll
          for (int i = 0; i < 4; ++i){
            int row = q*4 + i;
            float zr  = ex[0*256 + row*16 + nI];
            float inr = ex[1*256 + row*16 + nI];
            float hnr = ex[2*256 + row*16 + nI];
            float rv = fast_sigm(acc[i] + br);
            float zv = fast_sigm(zr + bz);
            float nv = fast_tanh(inr + bin + rv*(hnr + bhn));
            float hv = (1.f - zv)*nv + zv*hst[i];
            hst[i] = hv;
            unsigned int v = pst | f2bf(hv);
            st_pair(hOl + pb + row*256 + hc0 + nI, hOm + pb + row*256 + hc0 + nI, v);
            if (s == STEPS_-1)
              out[1024000 + gi_*16384 + (size_t)(b0+row)*256 + hc0 + nI] = hv;
          }
        }
      }
      // no loop-end barrier: ex/stage reuse gated by polls (see round-7 analysis)
    }
  }
}

extern "C" void kernel_launch(void* const* d_in, const int* in_sizes, int n_in,
                              void* d_out, int out_size, void* d_ws, size_t ws_size,
                              hipStream_t stream){
  (void)in_sizes; (void)n_in; (void)out_size; (void)ws_size;
  const float* features = (const float*)d_in[0];
  const int*   period   = (const int*)d_in[1];
  const float* rshift   = (const float*)d_in[3];
  const float* pembed   = (const float*)d_in[4];
  const float* fd1_w = (const float*)d_in[5];  const float* fd1_b = (const float*)d_in[6];
  const float* c1w   = (const float*)d_in[7];  const float* c1b   = (const float*)d_in[8];
  const float* c2w   = (const float*)d_in[9];  const float* c2b   = (const float*)d_in[10];
  const float* fd2_w = (const float*)d_in[11]; const float* fd2_b = (const float*)d_in[12];
  const float* sd1_w = (const float*)d_in[13]; const float* sd1_b = (const float*)d_in[14];
  const float* sd2_w = (const float*)d_in[15]; const float* sd2_b = (const float*)d_in[16];
  const float* g1_wi = (const float*)d_in[17]; const float* g1_bi = (const float*)d_in[18];
  const float* g1_wh = (const float*)d_in[19]; const float* g1_bh = (const float*)d_in[20];
  const float* g2_wi = (const float*)d_in[21]; const float* g2_bi = (const float*)d_in[22];
  const float* g2_wh = (const float*)d_in[23]; const float* g2_bh = (const float*)d_in[24];
  const float* g3_wi = (const float*)d_in[25]; const float* g3_bi = (const float*)d_in[26];
  const float* g3_wh = (const float*)d_in[27]; const float* g3_bh = (const float*)d_in[28];
  const float* out_w = (const float*)d_in[29]; const float* out_b = (const float*)d_in[30];

  char* ws = (char*)d_ws;
  size_t off = 0;
  auto alloc = [&](size_t bytes)->char*{
    char* p = ws + off; off += (bytes + 255) & ~(size_t)255; return p;
  };
  unsigned int* ctr  = (unsigned int*)alloc(512);
  unsigned int* tt2l = (unsigned int*)alloc(32768*4);
  unsigned int* tt2m = (unsigned int*)alloc(32768*4);
  unsigned int* h1l  = (unsigned int*)alloc(32768*4);
  unsigned int* h1m  = (unsigned int*)alloc(32768*4);
  unsigned int* h2l  = (unsigned int*)alloc(32768*4);
  unsigned int* h2m  = (unsigned int*)alloc(32768*4);
  unsigned int* h3l  = (unsigned int*)alloc(32768*4);
  unsigned int* h3m  = (unsigned int*)alloc(32768*4);
  float* tt1p = (float*)alloc((size_t)B_*STEPS_*COND_*4);   // [s][b][c]
  float* pr   = (float*)alloc((size_t)B_*STEPS_*SUB_*4);
  float* pi   = (float*)alloc((size_t)B_*STEPS_*SUB_*4);
  float* tbuf = (float*)alloc((size_t)B_*T_*COND_*4);
  float* x1   = (float*)alloc((size_t)B_*102*COND_*4);
  float* x2   = (float*)alloc((size_t)B_*100*COND_*4);
  float* cb   = (float*)alloc((size_t)B_*100*COND_*4);
  float* w1t  = (float*)alloc((size_t)768*256*4);
  float* w2t  = (float*)alloc((size_t)768*256*4);

  k_phase<<<64, 256, 0, stream>>>(period, rshift, pr, pi);
  k_prep<<<256, 256, 0, stream>>>(c1w, c2w, w1t, w2t, ctr);
  k_gemm<0><<<dim3(104,4), 256, 0, stream>>>(features, pembed, nullptr, period, fd1_w, fd1_b, tbuf);
  k_gemm<1><<<dim3(102,4), 256, 0, stream>>>(tbuf, nullptr, nullptr, nullptr, w1t, c1b, x1);
  k_gemm<2><<<dim3(100,4), 256, 0, stream>>>(x1, nullptr, nullptr, nullptr, w2t, c2b, x2);
  k_gemm<3><<<dim3(100,4), 256, 0, stream>>>(x2, nullptr, nullptr, nullptr, fd2_w, fd2_b, cb);
  k_gemm<4><<<dim3(400,4), 256, 0, stream>>>(cb, pr, pi, nullptr, sd1_w, sd1_b, tt1p);
  k_scan<<<512, 256, 0, stream>>>(sd1_w, sd2_w, sd2_b,
                                  g1_wi, g1_bi, g1_wh, g1_bh,
                                  g2_wi, g2_bi, g2_wh, g2_bh,
                                  g3_wi, g3_bi, g3_wh, g3_bh,
                                  out_w, out_b, tt1p, ctr,
                                  tt2l, tt2m, h1l, h1m, h2l, h2m, h3l, h3m,
                                  (float*)d_out);
}

// Round 9
// 7749.870 us; speedup vs baseline: 18.8655x; 1.7674x over previous
//
#include <hip/hip_runtime.h>
#include <hip/hip_bf16.h>
#include <math.h>

#define B_ 64
#define T_ 104
#define FEAT_ 20
#define PEMB_ 64
#define COND_ 256
#define SUB_ 40
#define NBF_ 100
#define STEPS_ 400

typedef short short8 __attribute__((ext_vector_type(8)));
typedef float floatx4 __attribute__((ext_vector_type(4)));

__device__ inline unsigned short f2bf(float x){
  unsigned int u = __float_as_uint(x);
  unsigned int r = (u + 0x7fffu + ((u >> 16) & 1u)) >> 16;
  return (unsigned short)r;
}
__device__ inline float fast_tanh(float x){
  float e = __expf(2.f*x);
  return 1.f - 2.f*__builtin_amdgcn_rcpf(e + 1.f);
}
__device__ inline float fast_sigm(float x){
  return __builtin_amdgcn_rcpf(1.f + __expf(-x));
}
__device__ inline floatx4 mfma16(short8 a, short8 b, floatx4 c){
  return __builtin_amdgcn_mfma_f32_16x16x32_bf16(a, b, c, 0, 0, 0);
}
__device__ inline unsigned long long ld_coh_u64(const unsigned long long* p){
  return __hip_atomic_load(p, __ATOMIC_RELAXED, __HIP_MEMORY_SCOPE_AGENT);
}
__device__ inline unsigned int ld_coh_u32(const unsigned int* p){
  return __hip_atomic_load(p, __ATOMIC_RELAXED, __HIP_MEMORY_SCOPE_AGENT);
}
__device__ inline void st_coh_u32(unsigned int* p, unsigned int v){
  __hip_atomic_store(p, v, __ATOMIC_RELAXED, __HIP_MEMORY_SCOPE_AGENT);
}
__device__ inline void st_coh_u16(unsigned short* p, unsigned short v){
  unsigned int vv = v;
  asm volatile("global_store_short %0, %1, off sc0 sc1" :: "v"(p), "v"(vv) : "memory");
}

// flags[stage][cluster][block]: one 64B slot each.
#define FLAG_IDX(st, g, sl) ((((st)*4 + (g))*16 + (sl))*16)

// ---------------- phase embedding ----------------
__global__ void k_phase(const int* __restrict__ period, const float* __restrict__ rshift,
                        float* __restrict__ pr, float* __restrict__ pi){
  int b = blockIdx.x;
  __shared__ float cumf[NBF_], w0f[NBF_];
  if (threadIdx.x == 0){
    double acc = 2.0*M_PI*(double)rshift[b];
    for (int f = 0; f < NBF_; ++f){
      double w0 = 2.0*M_PI/(double)period[b*T_ + 3 + f];
      cumf[f] = (float)fmod(acc, 2.0*M_PI);
      w0f[f] = (float)w0;
      acc += 160.0*w0;
    }
  }
  __syncthreads();
  for (int e = threadIdx.x; e < NBF_*160; e += blockDim.x){
    int f = e/160, j = e - f*160;
    float ph = cumf[f] + w0f[f]*(float)j;
    int s = f*4 + j/40, u = j%40;
    pr[((size_t)b*STEPS_ + s)*SUB_ + u] = cosf(ph);
    pi[((size_t)b*STEPS_ + s)*SUB_ + u] = sinf(ph);
  }
}

// ---------------- prep ----------------
__global__ void k_prep(const float* __restrict__ c1w, const float* __restrict__ c2w,
                       float* __restrict__ w1t, float* __restrict__ w2t,
                       unsigned int* __restrict__ flags, unsigned int* __restrict__ flagsT){
  size_t tid = (size_t)blockIdx.x*blockDim.x + threadIdx.x;
  size_t nt = (size_t)gridDim.x*blockDim.x;
  for (size_t e = tid; e < 4096; e += nt){ st_coh_u32(flags + e, 0u); st_coh_u32(flagsT + e, 0u); }
  for (size_t e = tid; e < 768u*256u; e += nt){
    int kk = (int)(e >> 8), o = (int)(e & 255);
    int i = kk & 255, kc = kk >> 8;
    w1t[e] = c1w[(size_t)o*768 + i*3 + kc];
    w2t[e] = c2w[(size_t)o*768 + i*3 + kc];
  }
}

// ---------------- generic fp32 tiled GEMM (M x K x 256) ----------------
template<int MODE>
__global__ __launch_bounds__(256) void k_gemm(
    const float* __restrict__ a0, const float* __restrict__ a1, const float* __restrict__ a2,
    const int* __restrict__ ip,
    const float* __restrict__ Bm, const float* __restrict__ bias, float* __restrict__ C)
{
  constexpr int KT = (MODE==0) ? 6 : (MODE==1||MODE==2) ? 48 : (MODE==3) ? 16 : 21;
  __shared__ float As[16][68];
  __shared__ float Bs[16][68];
  int tid = threadIdx.x;
  int m0 = blockIdx.x*64, n0 = blockIdx.y*64;
  int tx = tid & 15, ty = tid >> 4;
  float acc[4][4] = {};
  int am = m0 + (tid >> 2);
  int akq = (tid & 3)*4;
  int bk = tid >> 4;
  int bn4 = (tid & 15)*4;

  for (int kt = 0; kt < KT; ++kt){
    int kbase = kt*16;
    float av[4];
    {
      int k0 = kbase + akq;
      if constexpr (MODE==0){
        if (k0 < 20){
          const float* p = a0 + (size_t)am*FEAT_ + k0;
          #pragma unroll
          for (int u=0;u<4;++u) av[u] = p[u];
        } else if (k0 < 84){
          const float* p = a1 + (size_t)ip[am]*PEMB_ + (k0-20);
          #pragma unroll
          for (int u=0;u<4;++u) av[u] = p[u];
        } else { av[0]=av[1]=av[2]=av[3]=0.f; }
      } else if constexpr (MODE==1){
        int b = am/102, t2 = am - b*102;
        int i = k0 & 255, kc = k0 >> 8;
        const float* p = a0 + ((size_t)(b*T_ + t2 + kc))*COND_ + i;
        #pragma unroll
        for (int u=0;u<4;++u) av[u] = p[u];
      } else if constexpr (MODE==2){
        int b = am/100, t2 = am - b*100;
        int i = k0 & 255, kc = k0 >> 8;
        const float* p = a0 + ((size_t)(b*102 + t2 + kc))*COND_ + i;
        #pragma unroll
        for (int u=0;u<4;++u) av[u] = p[u];
      } else if constexpr (MODE==3){
        const float* p = a0 + (size_t)am*COND_ + k0;
        #pragma unroll
        for (int u=0;u<4;++u) av[u] = p[u];
      } else {
        int b = am/400, s = am - b*400;
        const float* p;
        if (k0 < 256)      p = a0 + ((size_t)(b*100 + (s>>2)))*COND_ + k0;
        else if (k0 < 296) p = a1 + ((size_t)(b*400 + s))*SUB_ + (k0-256);
        else               p = a2 + ((size_t)(b*400 + s))*SUB_ + (k0-296);
        #pragma unroll
        for (int u=0;u<4;++u) av[u] = p[u];
      }
    }
    float bv[4];
    {
      int kB = kbase + bk;
      if constexpr (MODE==0){
        if (kB < 84){
          const float* p = Bm + (size_t)kB*256 + n0 + bn4;
          #pragma unroll
          for (int u=0;u<4;++u) bv[u] = p[u];
        } else { bv[0]=bv[1]=bv[2]=bv[3]=0.f; }
      } else if constexpr (MODE==4){
        int krow = (kB < 256) ? kB : kB + 40;
        const float* p = Bm + (size_t)krow*256 + n0 + bn4;
        #pragma unroll
        for (int u=0;u<4;++u) bv[u] = p[u];
      } else {
        const float* p = Bm + (size_t)kB*256 + n0 + bn4;
        #pragma unroll
        for (int u=0;u<4;++u) bv[u] = p[u];
      }
    }
    #pragma unroll
    for (int u=0;u<4;++u) As[akq+u][tid>>2] = av[u];
    #pragma unroll
    for (int u=0;u<4;++u) Bs[bk][bn4+u] = bv[u];
    __syncthreads();
    #pragma unroll
    for (int k = 0; k < 16; ++k){
      float a4[4], b4[4];
      #pragma unroll
      for (int i=0;i<4;++i) a4[i] = As[k][ty*4+i];
      #pragma unroll
      for (int j=0;j<4;++j) b4[j] = Bs[k][tx*4+j];
      #pragma unroll
      for (int i=0;i<4;++i)
        #pragma unroll
        for (int j=0;j<4;++j)
          acc[i][j] += a4[i]*b4[j];
    }
    __syncthreads();
  }
  #pragma unroll
  for (int i=0;i<4;++i){
    int m = m0 + ty*4 + i;
    #pragma unroll
    for (int j=0;j<4;++j){
      int n = n0 + tx*4 + j;
      float v = acc[i][j] + bias[n];
      if constexpr (MODE == 4){
        int b = m/400, s = m - b*400;
        C[((size_t)s*64 + b)*256 + n] = v;     // transposed [s][b][c]
      } else {
        C[(size_t)m*256 + n] = fast_tanh(v);
      }
    }
  }
}

// ---------------- persistent AR scan (DIAG=0 real; DIAG=1 compute-only) ----------------
// 4 clusters x (16 S1 + 16 G1 + 16 G2 + 16 G3). Flag handshake (per-block 64B
// slots), MALL payloads. DIAG=1 removes all inter-block waits/flags (timing probe).
template<int DIAG>
__global__ __launch_bounds__(256, 1) void k_scan(
  const float* __restrict__ sd1_w, const float* __restrict__ sd2_w, const float* __restrict__ sd2_b,
  const float* __restrict__ g1_wi, const float* __restrict__ g1_bi, const float* __restrict__ g1_wh, const float* __restrict__ g1_bh,
  const float* __restrict__ g2_wi, const float* __restrict__ g2_bi, const float* __restrict__ g2_wh, const float* __restrict__ g2_bh,
  const float* __restrict__ g3_wi, const float* __restrict__ g3_bi, const float* __restrict__ g3_wh, const float* __restrict__ g3_bh,
  const float* __restrict__ out_w, const float* __restrict__ out_b,
  const float* __restrict__ tt1p,
  unsigned short* __restrict__ tt2buf, unsigned short* __restrict__ h1buf,
  unsigned short* __restrict__ h2buf, unsigned short* __restrict__ h3buf,
  unsigned int* __restrict__ flags, float* __restrict__ out)
{
  __shared__ __align__(16) char smem[65536];
  int tid = threadIdx.x;
  int lane = tid & 63, wave = tid >> 6;
  int q = lane >> 4, nI = lane & 15;
  int bI = blockIdx.x;
  int g = bI >> 6, rr = bI & 63;
  int set = rr >> 4, sl = rr & 15;
  int b0 = g*16;

  if (set == 0){
    // ===== S1: h3 -> prev -> tt1 -> tt2-slice =====
    char* outwF = smem;            // 24576
    char* sd1p0 = smem + 24576;    // 16384
    char* sd1p1 = smem + 40960;    // 4096
    char* sd2F  = smem + 45056;    // 8192
    char* stage = smem + 53248;    // 8192
    char* prevl = smem + 61440;    // 2304
    int col1 = sl*16 + nI;
    const unsigned int* fb3 = flags + FLAG_IDX(3, g, 0);
    unsigned int* myflag = flags + FLAG_IDX(0, g, sl);

    for (int t = wave; t < 24; t += 4){
      int nt = t >> 3, kk = t & 7;
      int c = nt*16 + nI;
      unsigned short v[8];
      #pragma unroll
      for (int j = 0; j < 8; ++j){
        int k = kk*32 + q*8 + j;
        v[j] = (c < 40) ? f2bf(out_w[(size_t)k*40 + c]) : (unsigned short)0;
      }
      *(short8*)(outwF + (t*64 + lane)*16) = *(short8*)v;
    }
    for (int t = wave; t < 16; t += 4){
      unsigned short v[8];
      #pragma unroll
      for (int j = 0; j < 8; ++j){
        int k = q*8 + j;
        v[j] = f2bf(sd1_w[(size_t)(256+k)*256 + t*16 + nI]);
      }
      *(short8*)(sd1p0 + (t*64 + lane)*16) = *(short8*)v;
    }
    {
      int nt = tid >> 4, ln = tid & 15;
      unsigned short v[8];
      #pragma unroll
      for (int j = 0; j < 8; ++j)
        v[j] = f2bf(sd1_w[(size_t)(256+32+j)*256 + nt*16 + ln]);
      *(short8*)(sd1p1 + tid*16) = *(short8*)v;
    }
    for (int t = wave; t < 8; t += 4){
      unsigned short v[8];
      #pragma unroll
      for (int j = 0; j < 8; ++j){
        int k = t*32 + q*8 + j;
        v[j] = f2bf(sd2_w[(size_t)k*256 + col1]);
      }
      *(short8*)(sd2F + (t*64 + lane)*16) = *(short8*)v;
    }
    for (int e = tid; e < 16*72; e += 256) *(unsigned short*)(prevl + e*2) = 0;
    float bout = 0.f;
    if (wave < 3){ int c = wave*16 + nI; if (c < 40) bout = out_b[c]; }
    float bsd2 = sd2_b[col1];
    __syncthreads();

    for (int s = 0; s <= STEPS_; ++s){
      // tt1p prefetch into regs (overlaps the poll)
      float t1r[16];
      if (s < STEPS_){
        const float* tb = tt1p + ((size_t)s*64 + b0)*256;
        #pragma unroll
        for (int ii = 0; ii < 4; ++ii){
          int c = (wave*4 + ii)*16 + nI;
          #pragma unroll
          for (int i = 0; i < 4; ++i)
            t1r[ii*4+i] = tb[(q*4+i)*256 + c];
        }
      }
      float pv4[4] = {0.f,0.f,0.f,0.f};
      if (s > 0){
        if constexpr (DIAG == 0){
          if (wave == 0 && lane < 16)
            while (ld_coh_u32(fb3 + lane*16) < (unsigned)s) {}
        }
        __syncthreads();
        const unsigned short* h3s = h3buf + ((size_t)((s+1)&1)*4 + g)*4096;
        for (int c = tid; c < 512; c += 256){
          int row = c >> 5, gc = c & 31;
          const unsigned long long* sp = (const unsigned long long*)(h3s + row*256 + gc*8);
          unsigned long long w0 = ld_coh_u64(sp), w1 = ld_coh_u64(sp+1);
          unsigned long long* dst = (unsigned long long*)(stage + (row*32 + (gc ^ (row & 7)))*16);
          dst[0]=w0; dst[1]=w1;
        }
        __syncthreads();
        if (wave < 3){
          floatx4 a0 = {0.f,0.f,0.f,0.f}, a1 = {0.f,0.f,0.f,0.f};
          #pragma unroll
          for (int kk = 0; kk < 8; kk += 2){
            short8 avA = *(const short8*)(stage + (nI*32 + ((kk*4+q) ^ (nI & 7)))*16);
            short8 bvA = *(const short8*)(outwF + ((wave*8+kk)*64 + lane)*16);
            a0 = mfma16(avA, bvA, a0);
            short8 avB = *(const short8*)(stage + (nI*32 + (((kk+1)*4+q) ^ (nI & 7)))*16);
            short8 bvB = *(const short8*)(outwF + ((wave*8+kk+1)*64 + lane)*16);
            a1 = mfma16(avB, bvB, a1);
          }
          floatx4 acc = a0 + a1;
          int c = wave*16 + nI;
          #pragma unroll
          for (int i = 0; i < 4; ++i){
            int row = q*4 + i;
            float pv = (c < 40) ? fast_tanh(acc[i] + bout) : 0.f;
            *(unsigned short*)(prevl + (row*72 + c)*2) = f2bf(pv);
            pv4[i] = pv;
          }
        }
      }
      if (s == STEPS_){
        if (sl == 0 && wave < 3){
          int c = wave*16 + nI;
          if (c < 40){
            #pragma unroll
            for (int i = 0; i < 4; ++i)
              out[(size_t)(b0+q*4+i)*16000 + (size_t)(s-1)*40 + c] = pv4[i];
          }
        }
        break;
      }
      __syncthreads();
      // tt1 = tanh(tt1p[s] + prev @ sd1p) -> stage
      #pragma unroll
      for (int ii = 0; ii < 4; ++ii){
        int nt = wave*4 + ii;
        floatx4 acc = {0.f,0.f,0.f,0.f};
        short8 a0v = *(const short8*)(prevl + nI*144 + q*16);
        short8 b0v = *(const short8*)(sd1p0 + (nt*64 + lane)*16);
        acc = mfma16(a0v, b0v, acc);
        short8 a1v = *(const short8*)(prevl + nI*144 + 64 + q*16);
        short8 b1v = {0,0,0,0,0,0,0,0};
        if (q == 0) b1v = *(const short8*)(sd1p1 + (nt*16 + nI)*16);
        acc = mfma16(a1v, b1v, acc);
        int c = nt*16 + nI;
        #pragma unroll
        for (int i = 0; i < 4; ++i){
          int row = q*4 + i;
          float tv = fast_tanh(acc[i] + t1r[ii*4+i]);
          int gc = c >> 3;
          *(unsigned short*)(stage + (row*32 + (gc ^ (row & 7)))*16 + (c & 7)*2) = f2bf(tv);
        }
      }
      __syncthreads();
      if (wave == 0){
        floatx4 a0 = {0.f,0.f,0.f,0.f}, a1 = {0.f,0.f,0.f,0.f};
        #pragma unroll
        for (int kk = 0; kk < 8; kk += 2){
          short8 avA = *(const short8*)(stage + (nI*32 + ((kk*4+q) ^ (nI & 7)))*16);
          short8 bvA = *(const short8*)(sd2F + (kk*64 + lane)*16);
          a0 = mfma16(avA, bvA, a0);
          short8 avB = *(const short8*)(stage + (nI*32 + (((kk+1)*4+q) ^ (nI & 7)))*16);
          short8 bvB = *(const short8*)(sd2F + ((kk+1)*64 + lane)*16);
          a1 = mfma16(avB, bvB, a1);
        }
        floatx4 acc = a0 + a1;
        unsigned short* t2 = tt2buf + ((size_t)(s&1)*4 + g)*4096;
        #pragma unroll
        for (int i = 0; i < 4; ++i){
          int row = q*4 + i;
          st_coh_u16(&t2[row*256 + col1], f2bf(fast_tanh(acc[i] + bsd2)));
        }
      }
      __syncthreads();   // drains tt2 MALL stores before flag
      if constexpr (DIAG == 0){
        if (tid == 0) st_coh_u32(myflag, (unsigned)(s+1));
      }
      // deferred sig output: issued AFTER the flag; drains during the next poll
      if (s > 0 && sl == 0 && wave < 3){
        int c = wave*16 + nI;
        if (c < 40){
          #pragma unroll
          for (int i = 0; i < 4; ++i)
            out[(size_t)(b0+q*4+i)*16000 + (size_t)(s-1)*40 + c] = pv4[i];
        }
      }
    }
  } else {
    // ===== GRU set =====
    int gi_ = set - 1;
    const float* wi = (gi_==0) ? g1_wi : (gi_==1) ? g2_wi : g3_wi;
    const float* wh = (gi_==0) ? g1_wh : (gi_==1) ? g2_wh : g3_wh;
    const float* bi = (gi_==0) ? g1_bi : (gi_==1) ? g2_bi : g3_bi;
    const float* bh = (gi_==0) ? g1_bh : (gi_==1) ? g2_bh : g3_bh;
    unsigned short* hOut = (gi_==0) ? h1buf : (gi_==1) ? h2buf : h3buf;
    const unsigned short* xBase = (gi_==0) ? tt2buf : (gi_==1) ? h1buf : h2buf;
    char* wlds  = smem;          // 49152
    char* stage = smem + 49152;  // 16384
    int hc0 = sl*16;
    const unsigned int* fbOwn  = flags + FLAG_IDX(set, g, 0);
    const unsigned int* fbPrev = flags + FLAG_IDX(set-1, g, 0);
    unsigned int* myflag = flags + FLAG_IDX(set, g, sl);

    for (int t = wave; t < 48; t += 4){
      unsigned short v[8];
      #pragma unroll
      for (int j = 0; j < 8; ++j){
        float w;
        if (t < 32){
          int k512 = (t & 15)*32 + q*8 + j;
          int col = ((t < 16) ? 0 : 256) + hc0 + nI;
          w = (k512 < 256) ? wi[(size_t)k512*768 + col] : wh[(size_t)(k512-256)*768 + col];
        } else if (t < 40){
          int k = (t-32)*32 + q*8 + j;
          w = wi[(size_t)k*768 + 512 + hc0 + nI];
        } else {
          int k = (t-40)*32 + q*8 + j;
          w = wh[(size_t)k*768 + 512 + hc0 + nI];
        }
        v[j] = f2bf(w);
      }
      *(short8*)(wlds + (t*64 + lane)*16) = *(short8*)v;
    }
    float br = 0.f, bz = 0.f, bin = 0.f, bhn = 0.f;
    if (wave == 0){
      int cg = hc0 + nI;
      br  = bi[cg] + bh[cg];
      bz  = bi[256+cg] + bh[256+cg];
      bin = bi[512+cg];
      bhn = bh[512+cg];
    }
    floatx4 hst = {0.f,0.f,0.f,0.f};
    __syncthreads();

    for (int s = 0; s < STEPS_; ++s){
      floatx4 ac0 = {0.f,0.f,0.f,0.f}, ac1 = {0.f,0.f,0.f,0.f};
      // --- phase A: own h(s-1) + h-half MFMAs ---
      if (s > 0){
        if constexpr (DIAG == 0){
          if (wave == 0 && lane < 16)
            while (ld_coh_u32(fbOwn + lane*16) < (unsigned)s) {}
        }
        __syncthreads();
        const unsigned short* hs = hOut + ((size_t)((s+1)&1)*4 + g)*4096;
        for (int c = tid; c < 512; c += 256){
          int row = c >> 5, gc = c & 31;
          const unsigned long long* sp = (const unsigned long long*)(hs + row*256 + gc*8);
          unsigned long long w0 = ld_coh_u64(sp), w1 = ld_coh_u64(sp+1);
          unsigned long long* dst = (unsigned long long*)(stage + (row*64 + ((32+gc) ^ (row & 7)))*16);
          dst[0]=w0; dst[1]=w1;
        }
        __syncthreads();
        if (wave < 2){
          int tb = wave*16;
          #pragma unroll
          for (int kt = 8; kt < 16; kt += 2){
            short8 avA = *(const short8*)(stage + (nI*64 + ((kt*4+q) ^ (nI & 7)))*16);
            short8 bvA = *(const short8*)(wlds + ((tb+kt)*64 + lane)*16);
            ac0 = mfma16(avA, bvA, ac0);
            short8 avB = *(const short8*)(stage + (nI*64 + (((kt+1)*4+q) ^ (nI & 7)))*16);
            short8 bvB = *(const short8*)(wlds + ((tb+kt+1)*64 + lane)*16);
            ac1 = mfma16(avB, bvB, ac1);
          }
        } else if (wave == 3){
          #pragma unroll
          for (int kt = 0; kt < 8; kt += 2){
            short8 avA = *(const short8*)(stage + (nI*64 + ((32 + kt*4+q) ^ (nI & 7)))*16);
            short8 bvA = *(const short8*)(wlds + ((40+kt)*64 + lane)*16);
            ac0 = mfma16(avA, bvA, ac0);
            short8 avB = *(const short8*)(stage + (nI*64 + ((32 + (kt+1)*4+q) ^ (nI & 7)))*16);
            short8 bvB = *(const short8*)(wlds + ((40+kt+1)*64 + lane)*16);
            ac1 = mfma16(avB, bvB, ac1);
          }
        }
      }
      // --- phase B: x(s) + x-half MFMAs ---
      if constexpr (DIAG == 0){
        if (wave == 0 && lane < 16)
          while (ld_coh_u32(fbPrev + lane*16) < (unsigned)(s+1)) {}
      }
      __syncthreads();
      const unsigned short* xs = xBase + ((size_t)(s&1)*4 + g)*4096;
      for (int c = tid; c < 512; c += 256){
        int row = c >> 5, gc = c & 31;
        const unsigned long long* sp = (const unsigned long long*)(xs + row*256 + gc*8);
        unsigned long long w0 = ld_coh_u64(sp), w1 = ld_coh_u64(sp+1);
        unsigned long long* dst = (unsigned long long*)(stage + (row*64 + (gc ^ (row & 7)))*16);
        dst[0]=w0; dst[1]=w1;
      }
      __syncthreads();
      if (wave < 2){
        int tb = wave*16;
        #pragma unroll
        for (int kt = 0; kt < 8; kt += 2){
          short8 avA = *(const short8*)(stage + (nI*64 + ((kt*4+q) ^ (nI & 7)))*16);
          short8 bvA = *(const short8*)(wlds + ((tb+kt)*64 + lane)*16);
          ac0 = mfma16(avA, bvA, ac0);
          short8 avB = *(const short8*)(stage + (nI*64 + (((kt+1)*4+q) ^ (nI & 7)))*16);
          short8 bvB = *(const short8*)(wlds + ((tb+kt+1)*64 + lane)*16);
          ac1 = mfma16(avB, bvB, ac1);
        }
      } else if (wave == 2){
        #pragma unroll
        for (int kt = 0; kt < 8; kt += 2){
          short8 avA = *(const short8*)(stage + (nI*64 + ((kt*4+q) ^ (nI & 7)))*16);
          short8 bvA = *(const short8*)(wlds + ((32+kt)*64 + lane)*16);
          ac0 = mfma16(avA, bvA, ac0);
          short8 avB = *(const short8*)(stage + (nI*64 + (((kt+1)*4+q) ^ (nI & 7)))*16);
          short8 bvB = *(const short8*)(wlds + ((32+kt+1)*64 + lane)*16);
          ac1 = mfma16(avB, bvB, ac1);
        }
      }
      floatx4 acc = ac0 + ac1;
      __syncthreads();
      float* ex = (float*)stage;
      if (wave >= 1){
        float* dst = ex + (wave-1)*256;
        #pragma unroll
        for (int i = 0; i < 4; ++i) dst[(q*4+i)*16 + nI] = acc[i];
      }
      __syncthreads();
      if (wave == 0){
        unsigned short* ho = hOut + ((size_t)(s&1)*4 + g)*4096;
        #pragma unroll
        for (int i = 0; i < 4; ++i){
          int row = q*4 + i;
          float zr  = ex[0*256 + row*16 + nI];
          float inr = ex[1*256 + row*16 + nI];
          float hnr = ex[2*256 + row*16 + nI];
          float rv = fast_sigm(acc[i] + br);
          float zv = fast_sigm(zr + bz);
          float nv = fast_tanh(inr + bin + rv*(hnr + bhn));
          float hv = (1.f - zv)*nv + zv*hst[i];
          hst[i] = hv;
          st_coh_u16(&ho[row*256 + hc0 + nI], f2bf(hv));
          if (s == STEPS_-1)
            out[1024000 + gi_*16384 + (size_t)(b0+row)*256 + hc0 + nI] = hv;
        }
      }
      __syncthreads();   // drains h MALL stores before flag
      if constexpr (DIAG == 0){
        if (tid == 0) st_coh_u32(myflag, (unsigned)(s+1));
      }
    }
  }
}

// ---------------- transport-only diagnostic: the flag/payload ring, no compute ----------------
__global__ __launch_bounds__(64, 1) void k_diag_t(unsigned int* __restrict__ flags,
                                                  unsigned int* __restrict__ pays){
  int lane = threadIdx.x & 63;
  int bI = blockIdx.x;
  int g = bI >> 6, rr = bI & 63;
  int set = rr >> 4, sl = rr & 15;
  unsigned int* myflag = flags + FLAG_IDX(set, g, sl);
  const unsigned int* fbOwn  = flags + FLAG_IDX(set, g, 0);
  const unsigned int* fbPrev = flags + FLAG_IDX((set+3)&3, g, 0);
  unsigned int* payOut = pays + set*32768;
  const unsigned int* payIn = pays + ((set+3)&3)*32768;

  for (int s = 0; s < STEPS_; ++s){
    if (s > 0 && lane < 16)
      while (ld_coh_u32(fbOwn + lane*16) < (unsigned)s) {}
    unsigned int tgt = (set == 0) ? (unsigned)s : (unsigned)(s+1);
    if (set != 0 || s > 0){
      if (lane < 16)
        while (ld_coh_u32(fbPrev + lane*16) < tgt) {}
    }
    // payload read (latency-representative)
    int pb = ((s&1)*4 + g)*4096 + lane*8;
    unsigned long long d0 = ld_coh_u64((const unsigned long long*)(payIn + pb));
    unsigned long long d1 = ld_coh_u64((const unsigned long long*)(payIn + pb + 2));
    // payload store (64 u32 per block)
    int ob = ((s&1)*4 + g)*4096;
    if (lane < 16){
      #pragma unroll
      for (int i = 0; i < 4; ++i)
        st_coh_u32(payOut + ob + i*256 + sl*16 + lane, (unsigned)(d0 + d1 + s));
    }
    asm volatile("s_waitcnt vmcnt(0)");
    if (lane == 0) st_coh_u32(myflag, (unsigned)(s+1));
  }
}

extern "C" void kernel_launch(void* const* d_in, const int* in_sizes, int n_in,
                              void* d_out, int out_size, void* d_ws, size_t ws_size,
                              hipStream_t stream){
  (void)in_sizes; (void)n_in; (void)out_size; (void)ws_size;
  const float* features = (const float*)d_in[0];
  const int*   period   = (const int*)d_in[1];
  const float* rshift   = (const float*)d_in[3];
  const float* pembed   = (const float*)d_in[4];
  const float* fd1_w = (const float*)d_in[5];  const float* fd1_b = (const float*)d_in[6];
  const float* c1w   = (const float*)d_in[7];  const float* c1b   = (const float*)d_in[8];
  const float* c2w   = (const float*)d_in[9];  const float* c2b   = (const float*)d_in[10];
  const float* fd2_w = (const float*)d_in[11]; const float* fd2_b = (const float*)d_in[12];
  const float* sd1_w = (const float*)d_in[13]; const float* sd1_b = (const float*)d_in[14];
  const float* sd2_w = (const float*)d_in[15]; const float* sd2_b = (const float*)d_in[16];
  const float* g1_wi = (const float*)d_in[17]; const float* g1_bi = (const float*)d_in[18];
  const float* g1_wh = (const float*)d_in[19]; const float* g1_bh = (const float*)d_in[20];
  const float* g2_wi = (const float*)d_in[21]; const float* g2_bi = (const float*)d_in[22];
  const float* g2_wh = (const float*)d_in[23]; const float* g2_bh = (const float*)d_in[24];
  const float* g3_wi = (const float*)d_in[25]; const float* g3_bi = (const float*)d_in[26];
  const float* g3_wh = (const float*)d_in[27]; const float* g3_bh = (const float*)d_in[28];
  const float* out_w = (const float*)d_in[29]; const float* out_b = (const float*)d_in[30];

  char* ws = (char*)d_ws;
  size_t off = 0;
  auto alloc = [&](size_t bytes)->char*{
    char* p = ws + off; off += (bytes + 255) & ~(size_t)255; return p;
  };
  unsigned int*  flags  = (unsigned int*)alloc(16384);
  unsigned int*  flagsT = (unsigned int*)alloc(16384);
  unsigned short* tt2b  = (unsigned short*)alloc(65536);
  unsigned short* h1b   = (unsigned short*)alloc(65536);
  unsigned short* h2b   = (unsigned short*)alloc(65536);
  unsigned short* h3b   = (unsigned short*)alloc(65536);
  unsigned int*  paysT  = (unsigned int*)alloc(131072*4);
  float* outC = (float*)alloc((size_t)1073152*4);          // compute-only scratch out
  float* tt1p = (float*)alloc((size_t)B_*STEPS_*COND_*4);  // [s][b][c]
  float* pr   = (float*)alloc((size_t)B_*STEPS_*SUB_*4);
  float* pi   = (float*)alloc((size_t)B_*STEPS_*SUB_*4);
  float* tbuf = (float*)alloc((size_t)B_*T_*COND_*4);
  float* x1   = (float*)alloc((size_t)B_*102*COND_*4);
  float* x2   = (float*)alloc((size_t)B_*100*COND_*4);
  float* cb   = (float*)alloc((size_t)B_*100*COND_*4);
  float* w1t  = (float*)alloc((size_t)768*256*4);
  float* w2t  = (float*)alloc((size_t)768*256*4);

  k_phase<<<64, 256, 0, stream>>>(period, rshift, pr, pi);
  k_prep<<<256, 256, 0, stream>>>(c1w, c2w, w1t, w2t, flags, flagsT);
  k_gemm<0><<<dim3(104,4), 256, 0, stream>>>(features, pembed, nullptr, period, fd1_w, fd1_b, tbuf);
  k_gemm<1><<<dim3(102,4), 256, 0, stream>>>(tbuf, nullptr, nullptr, nullptr, w1t, c1b, x1);
  k_gemm<2><<<dim3(100,4), 256, 0, stream>>>(x1, nullptr, nullptr, nullptr, w2t, c2b, x2);
  k_gemm<3><<<dim3(100,4), 256, 0, stream>>>(x2, nullptr, nullptr, nullptr, fd2_w, fd2_b, cb);
  k_gemm<4><<<dim3(400,4), 256, 0, stream>>>(cb, pr, pi, nullptr, sd1_w, sd1_b, tt1p);
  // real pass
  k_scan<0><<<256, 256, 0, stream>>>(sd1_w, sd2_w, sd2_b,
                                     g1_wi, g1_bi, g1_wh, g1_bh,
                                     g2_wi, g2_bi, g2_wh, g2_bh,
                                     g3_wi, g3_bi, g3_wh, g3_bh,
                                     out_w, out_b, tt1p,
                                     tt2b, h1b, h2b, h3b, flags, (float*)d_out);
  // diagnostics (scratch only; decompose step time via per-dispatch rocprof rows)
  k_diag_t<<<256, 64, 0, stream>>>(flagsT, paysT);
  k_scan<1><<<256, 256, 0, stream>>>(sd1_w, sd2_w, sd2_b,
                                     g1_wi, g1_bi, g1_wh, g1_bh,
                                     g2_wi, g2_bi, g2_wh, g2_bh,
                                     g3_wi, g3_bi, g3_wh, g3_bh,
                                     out_w, out_b, tt1p,
                                     tt2b, h1b, h2b, h3b, flags, outC);
}

// Round 10
// 5707.422 us; speedup vs baseline: 25.6167x; 1.3579x over previous
//
#include <hip/hip_runtime.h>
#include <hip/hip_bf16.h>
#include <math.h>

#define B_ 64
#define T_ 104
#define FEAT_ 20
#define PEMB_ 64
#define COND_ 256
#define SUB_ 40
#define NBF_ 100
#define STEPS_ 400

typedef short short8 __attribute__((ext_vector_type(8)));
typedef float floatx4 __attribute__((ext_vector_type(4)));

__device__ inline unsigned short f2bf(float x){
  unsigned int u = __float_as_uint(x);
  unsigned int r = (u + 0x7fffu + ((u >> 16) & 1u)) >> 16;
  return (unsigned short)r;
}
__device__ inline float fast_tanh(float x){
  float e = __expf(2.f*x);
  return 1.f - 2.f*__builtin_amdgcn_rcpf(e + 1.f);
}
__device__ inline float fast_sigm(float x){
  return __builtin_amdgcn_rcpf(1.f + __expf(-x));
}
__device__ inline floatx4 mfma16(short8 a, short8 b, floatx4 c){
  return __builtin_amdgcn_mfma_f32_16x16x32_bf16(a, b, c, 0, 0, 0);
}
__device__ inline unsigned long long ld_coh_u64(const unsigned long long* p){
  return __hip_atomic_load(p, __ATOMIC_RELAXED, __HIP_MEMORY_SCOPE_AGENT);
}
__device__ inline unsigned int ld_coh_u32(const unsigned int* p){
  return __hip_atomic_load(p, __ATOMIC_RELAXED, __HIP_MEMORY_SCOPE_AGENT);
}
__device__ inline void st_coh_u32(unsigned int* p, unsigned int v){
  __hip_atomic_store(p, v, __ATOMIC_RELAXED, __HIP_MEMORY_SCOPE_AGENT);
}
__device__ inline void st_coh_u16(unsigned short* p, unsigned short v){
  unsigned int vv = v;
  asm volatile("global_store_short %0, %1, off sc0 sc1" :: "v"(p), "v"(vv) : "memory");
}

// flags[stage][bg][block]: one 64B slot each.
#define FLAG_IDX(st, g, sl) ((((st)*4 + (g))*16 + (sl))*16)

// ---------------- phase embedding ----------------
__global__ void k_phase(const int* __restrict__ period, const float* __restrict__ rshift,
                        float* __restrict__ pr, float* __restrict__ pi){
  int b = blockIdx.x;
  __shared__ float cumf[NBF_], w0f[NBF_];
  if (threadIdx.x == 0){
    double acc = 2.0*M_PI*(double)rshift[b];
    for (int f = 0; f < NBF_; ++f){
      double w0 = 2.0*M_PI/(double)period[b*T_ + 3 + f];
      cumf[f] = (float)fmod(acc, 2.0*M_PI);
      w0f[f] = (float)w0;
      acc += 160.0*w0;
    }
  }
  __syncthreads();
  for (int e = threadIdx.x; e < NBF_*160; e += blockDim.x){
    int f = e/160, j = e - f*160;
    float ph = cumf[f] + w0f[f]*(float)j;
    int s = f*4 + j/40, u = j%40;
    pr[((size_t)b*STEPS_ + s)*SUB_ + u] = cosf(ph);
    pi[((size_t)b*STEPS_ + s)*SUB_ + u] = sinf(ph);
  }
}

// ---------------- prep ----------------
__global__ void k_prep(const float* __restrict__ c1w, const float* __restrict__ c2w,
                       float* __restrict__ w1t, float* __restrict__ w2t,
                       unsigned int* __restrict__ flags){
  size_t tid = (size_t)blockIdx.x*blockDim.x + threadIdx.x;
  size_t nt = (size_t)gridDim.x*blockDim.x;
  for (size_t e = tid; e < 4096; e += nt) st_coh_u32(flags + e, 0u);
  for (size_t e = tid; e < 768u*256u; e += nt){
    int kk = (int)(e >> 8), o = (int)(e & 255);
    int i = kk & 255, kc = kk >> 8;
    w1t[e] = c1w[(size_t)o*768 + i*3 + kc];
    w2t[e] = c2w[(size_t)o*768 + i*3 + kc];
  }
}

// ---------------- generic fp32 tiled GEMM (M x K x 256) ----------------
template<int MODE>
__global__ __launch_bounds__(256) void k_gemm(
    const float* __restrict__ a0, const float* __restrict__ a1, const float* __restrict__ a2,
    const int* __restrict__ ip,
    const float* __restrict__ Bm, const float* __restrict__ bias, float* __restrict__ C)
{
  constexpr int KT = (MODE==0) ? 6 : (MODE==1||MODE==2) ? 48 : (MODE==3) ? 16 : 21;
  __shared__ float As[16][68];
  __shared__ float Bs[16][68];
  int tid = threadIdx.x;
  int m0 = blockIdx.x*64, n0 = blockIdx.y*64;
  int tx = tid & 15, ty = tid >> 4;
  float acc[4][4] = {};
  int am = m0 + (tid >> 2);
  int akq = (tid & 3)*4;
  int bk = tid >> 4;
  int bn4 = (tid & 15)*4;

  for (int kt = 0; kt < KT; ++kt){
    int kbase = kt*16;
    float av[4];
    {
      int k0 = kbase + akq;
      if constexpr (MODE==0){
        if (k0 < 20){
          const float* p = a0 + (size_t)am*FEAT_ + k0;
          #pragma unroll
          for (int u=0;u<4;++u) av[u] = p[u];
        } else if (k0 < 84){
          const float* p = a1 + (size_t)ip[am]*PEMB_ + (k0-20);
          #pragma unroll
          for (int u=0;u<4;++u) av[u] = p[u];
        } else { av[0]=av[1]=av[2]=av[3]=0.f; }
      } else if constexpr (MODE==1){
        int b = am/102, t2 = am - b*102;
        int i = k0 & 255, kc = k0 >> 8;
        const float* p = a0 + ((size_t)(b*T_ + t2 + kc))*COND_ + i;
        #pragma unroll
        for (int u=0;u<4;++u) av[u] = p[u];
      } else if constexpr (MODE==2){
        int b = am/100, t2 = am - b*100;
        int i = k0 & 255, kc = k0 >> 8;
        const float* p = a0 + ((size_t)(b*102 + t2 + kc))*COND_ + i;
        #pragma unroll
        for (int u=0;u<4;++u) av[u] = p[u];
      } else if constexpr (MODE==3){
        const float* p = a0 + (size_t)am*COND_ + k0;
        #pragma unroll
        for (int u=0;u<4;++u) av[u] = p[u];
      } else {
        int b = am/400, s = am - b*400;
        const float* p;
        if (k0 < 256)      p = a0 + ((size_t)(b*100 + (s>>2)))*COND_ + k0;
        else if (k0 < 296) p = a1 + ((size_t)(b*400 + s))*SUB_ + (k0-256);
        else               p = a2 + ((size_t)(b*400 + s))*SUB_ + (k0-296);
        #pragma unroll
        for (int u=0;u<4;++u) av[u] = p[u];
      }
    }
    float bv[4];
    {
      int kB = kbase + bk;
      if constexpr (MODE==0){
        if (kB < 84){
          const float* p = Bm + (size_t)kB*256 + n0 + bn4;
          #pragma unroll
          for (int u=0;u<4;++u) bv[u] = p[u];
        } else { bv[0]=bv[1]=bv[2]=bv[3]=0.f; }
      } else if constexpr (MODE==4){
        int krow = (kB < 256) ? kB : kB + 40;
        const float* p = Bm + (size_t)krow*256 + n0 + bn4;
        #pragma unroll
        for (int u=0;u<4;++u) bv[u] = p[u];
      } else {
        const float* p = Bm + (size_t)kB*256 + n0 + bn4;
        #pragma unroll
        for (int u=0;u<4;++u) bv[u] = p[u];
      }
    }
    #pragma unroll
    for (int u=0;u<4;++u) As[akq+u][tid>>2] = av[u];
    #pragma unroll
    for (int u=0;u<4;++u) Bs[bk][bn4+u] = bv[u];
    __syncthreads();
    #pragma unroll
    for (int k = 0; k < 16; ++k){
      float a4[4], b4[4];
      #pragma unroll
      for (int i=0;i<4;++i) a4[i] = As[k][ty*4+i];
      #pragma unroll
      for (int j=0;j<4;++j) b4[j] = Bs[k][tx*4+j];
      #pragma unroll
      for (int i=0;i<4;++i)
        #pragma unroll
        for (int j=0;j<4;++j)
          acc[i][j] += a4[i]*b4[j];
    }
    __syncthreads();
  }
  #pragma unroll
  for (int i=0;i<4;++i){
    int m = m0 + ty*4 + i;
    #pragma unroll
    for (int j=0;j<4;++j){
      int n = n0 + tx*4 + j;
      float v = acc[i][j] + bias[n];
      if constexpr (MODE == 4){
        int b = m/400, s = m - b*400;
        C[((size_t)s*64 + b)*256 + n] = v;     // transposed [s][b][c]
      } else {
        C[(size_t)m*256 + n] = fast_tanh(v);
      }
    }
  }
}

// ---------------- persistent AR scan — pipelined ring ----------------
// 64 blocks = 16 S1 + 16 G1 + 16 G2 + 16 G3. Each stage block round-robins
// over 4 batch-groups (bg) per step: while bg0's flag/payload are in flight,
// the stage serves bg1..bg3 -> handoff transit leaves the critical path
// (step = 4 x service instead of 4 x (service+transit)). Weights in LDS are
// batch-independent; per-bg state is registers only.
__global__ __launch_bounds__(256, 1) void k_scan(
  const float* __restrict__ sd1_w, const float* __restrict__ sd2_w, const float* __restrict__ sd2_b,
  const float* __restrict__ g1_wi, const float* __restrict__ g1_bi, const float* __restrict__ g1_wh, const float* __restrict__ g1_bh,
  const float* __restrict__ g2_wi, const float* __restrict__ g2_bi, const float* __restrict__ g2_wh, const float* __restrict__ g2_bh,
  const float* __restrict__ g3_wi, const float* __restrict__ g3_bi, const float* __restrict__ g3_wh, const float* __restrict__ g3_bh,
  const float* __restrict__ out_w, const float* __restrict__ out_b,
  const float* __restrict__ tt1p,
  unsigned short* __restrict__ tt2buf, unsigned short* __restrict__ h1buf,
  unsigned short* __restrict__ h2buf, unsigned short* __restrict__ h3buf,
  unsigned int* __restrict__ flags, float* __restrict__ out)
{
  __shared__ __align__(16) char smem[65536];
  int tid = threadIdx.x;
  int lane = tid & 63, wave = tid >> 6;
  int q = lane >> 4, nI = lane & 15;
  int bI = blockIdx.x;
  int set = bI >> 4, sl = bI & 15;

  if (set == 0){
    // ===== S1: h3 -> prev -> tt1 -> tt2-slice, x4 batch groups =====
    char* outwF = smem;            // 24576
    char* sd1p0 = smem + 24576;    // 16384
    char* sd1p1 = smem + 40960;    // 4096
    char* sd2F  = smem + 45056;    // 8192
    char* stage = smem + 53248;    // 8192
    char* prevl = smem + 61440;    // 2304
    int col1 = sl*16 + nI;

    for (int t = wave; t < 24; t += 4){
      int nt = t >> 3, kk = t & 7;
      int c = nt*16 + nI;
      unsigned short v[8];
      #pragma unroll
      for (int j = 0; j < 8; ++j){
        int k = kk*32 + q*8 + j;
        v[j] = (c < 40) ? f2bf(out_w[(size_t)k*40 + c]) : (unsigned short)0;
      }
      *(short8*)(outwF + (t*64 + lane)*16) = *(short8*)v;
    }
    for (int t = wave; t < 16; t += 4){
      unsigned short v[8];
      #pragma unroll
      for (int j = 0; j < 8; ++j){
        int k = q*8 + j;
        v[j] = f2bf(sd1_w[(size_t)(256+k)*256 + t*16 + nI]);
      }
      *(short8*)(sd1p0 + (t*64 + lane)*16) = *(short8*)v;
    }
    {
      int nt = tid >> 4, ln = tid & 15;
      unsigned short v[8];
      #pragma unroll
      for (int j = 0; j < 8; ++j)
        v[j] = f2bf(sd1_w[(size_t)(256+32+j)*256 + nt*16 + ln]);
      *(short8*)(sd1p1 + tid*16) = *(short8*)v;
    }
    for (int t = wave; t < 8; t += 4){
      unsigned short v[8];
      #pragma unroll
      for (int j = 0; j < 8; ++j){
        int k = t*32 + q*8 + j;
        v[j] = f2bf(sd2_w[(size_t)k*256 + col1]);
      }
      *(short8*)(sd2F + (t*64 + lane)*16) = *(short8*)v;
    }
    for (int e = tid; e < 16*72; e += 256) *(unsigned short*)(prevl + e*2) = 0;
    float bout = 0.f;
    if (wave < 3){ int c = wave*16 + nI; if (c < 40) bout = out_b[c]; }
    float bsd2 = sd2_b[col1];
    __syncthreads();

    for (int s = 0; s <= STEPS_; ++s){
      for (int bg = 0; bg < 4; ++bg){
        int b0 = bg*16;
        // tt1p prefetch (overlaps poll + payload latency)
        float t1r[16];
        if (s < STEPS_){
          const float* tb = tt1p + ((size_t)s*64 + b0)*256;
          #pragma unroll
          for (int ii = 0; ii < 4; ++ii){
            int c = (wave*4 + ii)*16 + nI;
            #pragma unroll
            for (int i = 0; i < 4; ++i)
              t1r[ii*4+i] = tb[(q*4+i)*256 + c];
          }
        }
        float pv4[4] = {0.f,0.f,0.f,0.f};
        if (s > 0){
          if (wave == 0 && lane < 16){
            const unsigned int* fp = flags + FLAG_IDX(3, bg, lane);
            while (ld_coh_u32(fp) < (unsigned)s) {}
          }
          __syncthreads();
          const unsigned short* h3s = h3buf + ((size_t)((s+1)&1)*4 + bg)*4096;
          for (int c = tid; c < 512; c += 256){
            int row = c >> 5, gc = c & 31;
            const unsigned long long* sp = (const unsigned long long*)(h3s + row*256 + gc*8);
            unsigned long long w0 = ld_coh_u64(sp), w1 = ld_coh_u64(sp+1);
            unsigned long long* dst = (unsigned long long*)(stage + (row*32 + (gc ^ (row & 7)))*16);
            dst[0]=w0; dst[1]=w1;
          }
          __syncthreads();
          if (wave < 3){
            floatx4 a0 = {0.f,0.f,0.f,0.f}, a1 = {0.f,0.f,0.f,0.f};
            #pragma unroll
            for (int kk = 0; kk < 8; kk += 2){
              short8 avA = *(const short8*)(stage + (nI*32 + ((kk*4+q) ^ (nI & 7)))*16);
              short8 bvA = *(const short8*)(outwF + ((wave*8+kk)*64 + lane)*16);
              a0 = mfma16(avA, bvA, a0);
              short8 avB = *(const short8*)(stage + (nI*32 + (((kk+1)*4+q) ^ (nI & 7)))*16);
              short8 bvB = *(const short8*)(outwF + ((wave*8+kk+1)*64 + lane)*16);
              a1 = mfma16(avB, bvB, a1);
            }
            floatx4 acc = a0 + a1;
            int c = wave*16 + nI;
            #pragma unroll
            for (int i = 0; i < 4; ++i){
              int row = q*4 + i;
              float pv = (c < 40) ? fast_tanh(acc[i] + bout) : 0.f;
              *(unsigned short*)(prevl + (row*72 + c)*2) = f2bf(pv);
              pv4[i] = pv;
            }
          }
        }
        if (s == STEPS_){
          if (sl == 0 && wave < 3){
            int c = wave*16 + nI;
            if (c < 40){
              #pragma unroll
              for (int i = 0; i < 4; ++i)
                out[(size_t)(b0+q*4+i)*16000 + (size_t)(s-1)*40 + c] = pv4[i];
            }
          }
          continue;
        }
        __syncthreads();
        // tt1 = tanh(tt1p[s] + prev @ sd1p) -> stage
        #pragma unroll
        for (int ii = 0; ii < 4; ++ii){
          int nt = wave*4 + ii;
          floatx4 acc = {0.f,0.f,0.f,0.f};
          short8 a0v = *(const short8*)(prevl + nI*144 + q*16);
          short8 b0v = *(const short8*)(sd1p0 + (nt*64 + lane)*16);
          acc = mfma16(a0v, b0v, acc);
          short8 a1v = *(const short8*)(prevl + nI*144 + 64 + q*16);
          short8 b1v = {0,0,0,0,0,0,0,0};
          if (q == 0) b1v = *(const short8*)(sd1p1 + (nt*16 + nI)*16);
          acc = mfma16(a1v, b1v, acc);
          int c = nt*16 + nI;
          #pragma unroll
          for (int i = 0; i < 4; ++i){
            int row = q*4 + i;
            float tv = fast_tanh(acc[i] + t1r[ii*4+i]);
            int gc = c >> 3;
            *(unsigned short*)(stage + (row*32 + (gc ^ (row & 7)))*16 + (c & 7)*2) = f2bf(tv);
          }
        }
        __syncthreads();
        if (wave == 0){
          floatx4 a0 = {0.f,0.f,0.f,0.f}, a1 = {0.f,0.f,0.f,0.f};
          #pragma unroll
          for (int kk = 0; kk < 8; kk += 2){
            short8 avA = *(const short8*)(stage + (nI*32 + ((kk*4+q) ^ (nI & 7)))*16);
            short8 bvA = *(const short8*)(sd2F + (kk*64 + lane)*16);
            a0 = mfma16(avA, bvA, a0);
            short8 avB = *(const short8*)(stage + (nI*32 + (((kk+1)*4+q) ^ (nI & 7)))*16);
            short8 bvB = *(const short8*)(sd2F + ((kk+1)*64 + lane)*16);
            a1 = mfma16(avB, bvB, a1);
          }
          floatx4 acc = a0 + a1;
          unsigned short* t2 = tt2buf + ((size_t)(s&1)*4 + bg)*4096;
          #pragma unroll
          for (int i = 0; i < 4; ++i){
            int row = q*4 + i;
            st_coh_u16(&t2[row*256 + col1], f2bf(fast_tanh(acc[i] + bsd2)));
          }
          asm volatile("s_waitcnt vmcnt(0)" ::: "memory");  // drain tt2 before flag (wave0 only)
        }
        if (tid == 0) st_coh_u32(flags + FLAG_IDX(0, bg, sl), (unsigned)(s+1));
        // deferred sig output (off the signal path)
        if (s > 0 && sl == 0 && wave < 3){
          int c = wave*16 + nI;
          if (c < 40){
            #pragma unroll
            for (int i = 0; i < 4; ++i)
              out[(size_t)(b0+q*4+i)*16000 + (size_t)(s-1)*40 + c] = pv4[i];
          }
        }
      }
    }
  } else {
    // ===== GRU stage (set-1 = GRU index), x4 batch groups =====
    int gi_ = set - 1;
    const float* wi = (gi_==0) ? g1_wi : (gi_==1) ? g2_wi : g3_wi;
    const float* wh = (gi_==0) ? g1_wh : (gi_==1) ? g2_wh : g3_wh;
    const float* bi = (gi_==0) ? g1_bi : (gi_==1) ? g2_bi : g3_bi;
    const float* bh = (gi_==0) ? g1_bh : (gi_==1) ? g2_bh : g3_bh;
    unsigned short* hOut = (gi_==0) ? h1buf : (gi_==1) ? h2buf : h3buf;
    const unsigned short* xBase = (gi_==0) ? tt2buf : (gi_==1) ? h1buf : h2buf;
    char* wlds  = smem;          // 49152
    char* stage = smem + 49152;  // 16384 (rows x 64 chunks: x 0..31, h 32..63)
    float* ex = (float*)stage;   // aliased exchange (written after all stage reads)
    int hc0 = sl*16;

    for (int t = wave; t < 48; t += 4){
      unsigned short v[8];
      #pragma unroll
      for (int j = 0; j < 8; ++j){
        float w;
        if (t < 32){
          int k512 = (t & 15)*32 + q*8 + j;
          int col = ((t < 16) ? 0 : 256) + hc0 + nI;
          w = (k512 < 256) ? wi[(size_t)k512*768 + col] : wh[(size_t)(k512-256)*768 + col];
        } else if (t < 40){
          int k = (t-32)*32 + q*8 + j;
          w = wi[(size_t)k*768 + 512 + hc0 + nI];
        } else {
          int k = (t-40)*32 + q*8 + j;
          w = wh[(size_t)k*768 + 512 + hc0 + nI];
        }
        v[j] = f2bf(w);
      }
      *(short8*)(wlds + (t*64 + lane)*16) = *(short8*)v;
    }
    float br = 0.f, bz = 0.f, bin = 0.f, bhn = 0.f;
    if (wave == 0){
      int cg = hc0 + nI;
      br  = bi[cg] + bh[cg];
      bz  = bi[256+cg] + bh[256+cg];
      bin = bi[512+cg];
      bhn = bh[512+cg];
    }
    floatx4 hstA[4];
    #pragma unroll
    for (int b = 0; b < 4; ++b) hstA[b] = (floatx4){0.f,0.f,0.f,0.f};
    __syncthreads();

    for (int s = 0; s < STEPS_; ++s){
      for (int bg = 0; bg < 4; ++bg){
        int b0 = bg*16;
        // fused poll: lanes 0..15 own-stage (h siblings), 16..31 upstream x
        if (wave == 0 && lane < 32){
          const unsigned int* fp = (lane < 16)
            ? flags + FLAG_IDX(set, bg, lane)
            : flags + FLAG_IDX(set-1, bg, lane-16);
          unsigned int tgt = (lane < 16) ? (unsigned)s : (unsigned)(s+1);
          if (!(lane < 16 && s == 0))
            while (ld_coh_u32(fp) < tgt) {}
        }
        __syncthreads();
        if (s > 0){
          const unsigned short* hs = hOut + ((size_t)((s+1)&1)*4 + bg)*4096;
          for (int c = tid; c < 512; c += 256){
            int row = c >> 5, gc = c & 31;
            const unsigned long long* sp = (const unsigned long long*)(hs + row*256 + gc*8);
            unsigned long long w0 = ld_coh_u64(sp), w1 = ld_coh_u64(sp+1);
            unsigned long long* dst = (unsigned long long*)(stage + (row*64 + ((32+gc) ^ (row & 7)))*16);
            dst[0]=w0; dst[1]=w1;
          }
        }
        {
          const unsigned short* xs = xBase + ((size_t)(s&1)*4 + bg)*4096;
          for (int c = tid; c < 512; c += 256){
            int row = c >> 5, gc = c & 31;
            const unsigned long long* sp = (const unsigned long long*)(xs + row*256 + gc*8);
            unsigned long long w0 = ld_coh_u64(sp), w1 = ld_coh_u64(sp+1);
            unsigned long long* dst = (unsigned long long*)(stage + (row*64 + (gc ^ (row & 7)))*16);
            dst[0]=w0; dst[1]=w1;
          }
        }
        __syncthreads();
        floatx4 ac0 = {0.f,0.f,0.f,0.f}, ac1 = {0.f,0.f,0.f,0.f};
        if (wave < 2){
          int tb = wave*16;
          int kend = (s > 0) ? 16 : 8;
          for (int kt = 0; kt < kend; kt += 2){
            short8 avA = *(const short8*)(stage + (nI*64 + ((kt*4+q) ^ (nI & 7)))*16);
            short8 bvA = *(const short8*)(wlds + ((tb+kt)*64 + lane)*16);
            ac0 = mfma16(avA, bvA, ac0);
            short8 avB = *(const short8*)(stage + (nI*64 + (((kt+1)*4+q) ^ (nI & 7)))*16);
            short8 bvB = *(const short8*)(wlds + ((tb+kt+1)*64 + lane)*16);
            ac1 = mfma16(avB, bvB, ac1);
          }
        } else if (wave == 2){
          #pragma unroll
          for (int kt = 0; kt < 8; kt += 2){
            short8 avA = *(const short8*)(stage + (nI*64 + ((kt*4+q) ^ (nI & 7)))*16);
            short8 bvA = *(const short8*)(wlds + ((32+kt)*64 + lane)*16);
            ac0 = mfma16(avA, bvA, ac0);
            short8 avB = *(const short8*)(stage + (nI*64 + (((kt+1)*4+q) ^ (nI & 7)))*16);
            short8 bvB = *(const short8*)(wlds + ((32+kt+1)*64 + lane)*16);
            ac1 = mfma16(avB, bvB, ac1);
          }
        } else if (s > 0){
          #pragma unroll
          for (int kt = 0; kt < 8; kt += 2){
            short8 avA = *(const short8*)(stage + (nI*64 + ((32 + kt*4+q) ^ (nI & 7)))*16);
            short8 bvA = *(const short8*)(wlds + ((40+kt)*64 + lane)*16);
            ac0 = mfma16(avA, bvA, ac0);
            short8 avB = *(const short8*)(stage + (nI*64 + ((32 + (kt+1)*4+q) ^ (nI & 7)))*16);
            short8 bvB = *(const short8*)(wlds + ((40+kt+1)*64 + lane)*16);
            ac1 = mfma16(avB, bvB, ac1);
          }
        }
        floatx4 acc = ac0 + ac1;
        __syncthreads();
        if (wave >= 1){
          float* dst = ex + (wave-1)*256;
          #pragma unroll
          for (int i = 0; i < 4; ++i) dst[(q*4+i)*16 + nI] = acc[i];
        }
        __syncthreads();
        if (wave == 0){
          unsigned short* ho = hOut + ((size_t)(s&1)*4 + bg)*4096;
          #pragma unroll
          for (int i = 0; i < 4; ++i){
            int row = q*4 + i;
            float zr  = ex[0*256 + row*16 + nI];
            float inr = ex[1*256 + row*16 + nI];
            float hnr = ex[2*256 + row*16 + nI];
            float rv = fast_sigm(acc[i] + br);
            float zv = fast_sigm(zr + bz);
            float nv = fast_tanh(inr + bin + rv*(hnr + bhn));
            float hv = (1.f - zv)*nv + zv*hstA[bg][i];
            hstA[bg][i] = hv;
            st_coh_u16(&ho[row*256 + hc0 + nI], f2bf(hv));
            if (s == STEPS_-1)
              out[1024000 + gi_*16384 + (size_t)(b0+row)*256 + hc0 + nI] = hv;
          }
          asm volatile("s_waitcnt vmcnt(0)" ::: "memory");  // drain h before flag (wave0 only)
        }
        if (tid == 0) st_coh_u32(flags + FLAG_IDX(set, bg, sl), (unsigned)(s+1));
      }
    }
  }
}

extern "C" void kernel_launch(void* const* d_in, const int* in_sizes, int n_in,
                              void* d_out, int out_size, void* d_ws, size_t ws_size,
                              hipStream_t stream){
  (void)in_sizes; (void)n_in; (void)out_size; (void)ws_size;
  const float* features = (const float*)d_in[0];
  const int*   period   = (const int*)d_in[1];
  const float* rshift   = (const float*)d_in[3];
  const float* pembed   = (const float*)d_in[4];
  const float* fd1_w = (const float*)d_in[5];  const float* fd1_b = (const float*)d_in[6];
  const float* c1w   = (const float*)d_in[7];  const float* c1b   = (const float*)d_in[8];
  const float* c2w   = (const float*)d_in[9];  const float* c2b   = (const float*)d_in[10];
  const float* fd2_w = (const float*)d_in[11]; const float* fd2_b = (const float*)d_in[12];
  const float* sd1_w = (const float*)d_in[13]; const float* sd1_b = (const float*)d_in[14];
  const float* sd2_w = (const float*)d_in[15]; const float* sd2_b = (const float*)d_in[16];
  const float* g1_wi = (const float*)d_in[17]; const float* g1_bi = (const float*)d_in[18];
  const float* g1_wh = (const float*)d_in[19]; const float* g1_bh = (const float*)d_in[20];
  const float* g2_wi = (const float*)d_in[21]; const float* g2_bi = (const float*)d_in[22];
  const float* g2_wh = (const float*)d_in[23]; const float* g2_bh = (const float*)d_in[24];
  const float* g3_wi = (const float*)d_in[25]; const float* g3_bi = (const float*)d_in[26];
  const float* g3_wh = (const float*)d_in[27]; const float* g3_bh = (const float*)d_in[28];
  const float* out_w = (const float*)d_in[29]; const float* out_b = (const float*)d_in[30];

  char* ws = (char*)d_ws;
  size_t off = 0;
  auto alloc = [&](size_t bytes)->char*{
    char* p = ws + off; off += (bytes + 255) & ~(size_t)255; return p;
  };
  unsigned int*  flags  = (unsigned int*)alloc(16384);
  unsigned short* tt2b  = (unsigned short*)alloc(65536);
  unsigned short* h1b   = (unsigned short*)alloc(65536);
  unsigned short* h2b   = (unsigned short*)alloc(65536);
  unsigned short* h3b   = (unsigned short*)alloc(65536);
  float* tt1p = (float*)alloc((size_t)B_*STEPS_*COND_*4);  // [s][b][c]
  float* pr   = (float*)alloc((size_t)B_*STEPS_*SUB_*4);
  float* pi   = (float*)alloc((size_t)B_*STEPS_*SUB_*4);
  float* tbuf = (float*)alloc((size_t)B_*T_*COND_*4);
  float* x1   = (float*)alloc((size_t)B_*102*COND_*4);
  float* x2   = (float*)alloc((size_t)B_*100*COND_*4);
  float* cb   = (float*)alloc((size_t)B_*100*COND_*4);
  float* w1t  = (float*)alloc((size_t)768*256*4);
  float* w2t  = (float*)alloc((size_t)768*256*4);

  k_phase<<<64, 256, 0, stream>>>(period, rshift, pr, pi);
  k_prep<<<256, 256, 0, stream>>>(c1w, c2w, w1t, w2t, flags);
  k_gemm<0><<<dim3(104,4), 256, 0, stream>>>(features, pembed, nullptr, period, fd1_w, fd1_b, tbuf);
  k_gemm<1><<<dim3(102,4), 256, 0, stream>>>(tbuf, nullptr, nullptr, nullptr, w1t, c1b, x1);
  k_gemm<2><<<dim3(100,4), 256, 0, stream>>>(x1, nullptr, nullptr, nullptr, w2t, c2b, x2);
  k_gemm<3><<<dim3(100,4), 256, 0, stream>>>(x2, nullptr, nullptr, nullptr, fd2_w, fd2_b, cb);
  k_gemm<4><<<dim3(400,4), 256, 0, stream>>>(cb, pr, pi, nullptr, sd1_w, sd1_b, tt1p);
  k_scan<<<64, 256, 0, stream>>>(sd1_w, sd2_w, sd2_b,
                                 g1_wi, g1_bi, g1_wh, g1_bh,
                                 g2_wi, g2_bi, g2_wh, g2_bh,
                                 g3_wi, g3_bi, g3_wh, g3_bh,
                                 out_w, out_b, tt1p,
                                 tt2b, h1b, h2b, h3b, flags, (float*)d_out);
}